// Round 1
// baseline (2554.605 us; speedup 1.0000x reference)
//
#include <hip/hip_runtime.h>
#include <hip/hip_bf16.h>

#define NL 8
#define NV 50257
#define NC 1024
#define NH 16
#define NT 1024
#define NFF 4096
#define NB 2
#define NM (NB*NT)   // 2048 rows

typedef __attribute__((ext_vector_type(8))) short bf16x8;
typedef __attribute__((ext_vector_type(4))) float f32x4;

__device__ __forceinline__ unsigned short f2bf(float f) {
    union { float f; unsigned u; } a; a.f = f;
    unsigned r = a.u + 0x7FFFu + ((a.u >> 16) & 1u);
    return (unsigned short)(r >> 16);
}

// ---------------- embedding: x[b,t,:] = tok_emb[idx[b,t],:] + pos_emb[t,:]
__global__ __launch_bounds__(256) void embed_kernel(
    const int* __restrict__ idx, const float* __restrict__ te,
    const float* __restrict__ pe, float* __restrict__ x) {
    int row = blockIdx.x;            // 0..2047 = b*1024 + t
    int t = row & (NT - 1);
    int id = idx[row];
    const float4 a = reinterpret_cast<const float4*>(te + (size_t)id * NC)[threadIdx.x];
    const float4 b = reinterpret_cast<const float4*>(pe + (size_t)t * NC)[threadIdx.x];
    float4 o; o.x = a.x + b.x; o.y = a.y + b.y; o.z = a.z + b.z; o.w = a.w + b.w;
    reinterpret_cast<float4*>(x + (size_t)row * NC)[threadIdx.x] = o;
}

// ---------------- f32 -> bf16 bulk convert (tok_emb)
__global__ __launch_bounds__(256) void cvt_bf16_kernel(
    const float* __restrict__ in, unsigned short* __restrict__ out, size_t n4) {
    size_t i = (size_t)blockIdx.x * 256 + threadIdx.x;
    if (i >= n4) return;
    float4 v = reinterpret_cast<const float4*>(in)[i];
    uint2 u;
    u.x = (unsigned)f2bf(v.x) | ((unsigned)f2bf(v.y) << 16);
    u.y = (unsigned)f2bf(v.z) | ((unsigned)f2bf(v.w) << 16);
    reinterpret_cast<uint2*>(out)[i] = u;
}

// ---------------- weight transpose+convert: W[K][N] f32 -> Wt[N][K] bf16
__global__ __launch_bounds__(256) void wtrans_kernel(
    const float* __restrict__ W, unsigned short* __restrict__ Wt, int K, int N) {
    __shared__ float tile[32][33];
    int n0 = blockIdx.x * 32, k0 = blockIdx.y * 32;
    int tx = threadIdx.x, ty = threadIdx.y;  // (32,8)
#pragma unroll
    for (int i = 0; i < 4; ++i)
        tile[ty + i * 8][tx] = W[(size_t)(k0 + ty + i * 8) * N + n0 + tx];
    __syncthreads();
#pragma unroll
    for (int i = 0; i < 4; ++i)
        Wt[(size_t)(n0 + ty + i * 8) * K + k0 + tx] = f2bf(tile[tx][ty + i * 8]);
}

// ---------------- layernorm (f32 in -> bf16 out), one block per row, C=1024
__global__ __launch_bounds__(256) void ln_kernel(
    const float* __restrict__ x, const float* __restrict__ gam,
    const float* __restrict__ bet, unsigned short* __restrict__ out) {
    __shared__ float red[4];
    int row = blockIdx.x, tid = threadIdx.x;
    const float4 v = reinterpret_cast<const float4*>(x + (size_t)row * NC)[tid];
    float s = v.x + v.y + v.z + v.w;
#pragma unroll
    for (int m = 32; m >= 1; m >>= 1) s += __shfl_xor(s, m, 64);
    if ((tid & 63) == 0) red[tid >> 6] = s;
    __syncthreads();
    float mean = (red[0] + red[1] + red[2] + red[3]) * (1.0f / NC);
    __syncthreads();
    float dx = v.x - mean, dy = v.y - mean, dz = v.z - mean, dw = v.w - mean;
    float q = dx * dx + dy * dy + dz * dz + dw * dw;
#pragma unroll
    for (int m = 32; m >= 1; m >>= 1) q += __shfl_xor(q, m, 64);
    if ((tid & 63) == 0) red[tid >> 6] = q;
    __syncthreads();
    float var = (red[0] + red[1] + red[2] + red[3]) * (1.0f / NC);
    float rstd = rsqrtf(var + 1e-5f);
    int c = tid * 4;
    const float4 g4 = reinterpret_cast<const float4*>(gam)[tid];
    const float4 b4 = reinterpret_cast<const float4*>(bet)[tid];
    uint2 u;
    u.x = (unsigned)f2bf(dx * rstd * g4.x + b4.x) |
          ((unsigned)f2bf(dy * rstd * g4.y + b4.y) << 16);
    u.y = (unsigned)f2bf(dz * rstd * g4.z + b4.z) |
          ((unsigned)f2bf(dw * rstd * g4.w + b4.w) << 16);
    reinterpret_cast<uint2*>(out + (size_t)row * NC + c)[0] = u;
}

// ---------------- GEMM: C[M][N] = A[M][K](bf16) * Bt[N][K](bf16)^T  (+bias,+act,+resid)
// 128x128 tile, BK=32, 4 waves, each wave 64x64 via 4x4 mfma_16x16x32 frags.
template<int ACT, bool BIAS, bool RESID, bool OUTBF16, bool NEDGE>
__global__ __launch_bounds__(256) void gemm_kernel(
    const unsigned short* __restrict__ A, const unsigned short* __restrict__ Bt,
    const float* __restrict__ bias, const float* __restrict__ resid,
    void* __restrict__ Cout, int N, int K, int ldc) {
    __shared__ unsigned short As[128][40];
    __shared__ unsigned short Bs[128][40];
    const int tid = threadIdx.x;
    const int lane = tid & 63;
    const int wave = tid >> 6;
    const int wm = wave >> 1, wn = wave & 1;
    const int lr = lane & 15, lg = lane >> 4;
    const int m0 = blockIdx.y * 128, n0 = blockIdx.x * 128;

    const f32x4 zero4 = {0.0f, 0.0f, 0.0f, 0.0f};
    f32x4 acc[4][4];
#pragma unroll
    for (int i = 0; i < 4; ++i)
#pragma unroll
        for (int j = 0; j < 4; ++j) acc[i][j] = zero4;

    for (int k0 = 0; k0 < K; k0 += 32) {
        __syncthreads();
#pragma unroll
        for (int i = 0; i < 2; ++i) {
            int chunk = tid + i * 256;          // 0..511
            int row = chunk >> 2;
            int col = (chunk & 3) * 8;
            bf16x8 av = *reinterpret_cast<const bf16x8*>(A + (size_t)(m0 + row) * K + k0 + col);
            *reinterpret_cast<bf16x8*>(&As[row][col]) = av;
            int nrow = n0 + row;
            if (NEDGE) nrow = (nrow < N - 1) ? nrow : (N - 1);
            bf16x8 bv = *reinterpret_cast<const bf16x8*>(Bt + (size_t)nrow * K + k0 + col);
            *reinterpret_cast<bf16x8*>(&Bs[row][col]) = bv;
        }
        __syncthreads();
        bf16x8 af[4], bfr[4];
#pragma unroll
        for (int f = 0; f < 4; ++f) {
            af[f]  = *reinterpret_cast<const bf16x8*>(&As[wm * 64 + f * 16 + lr][lg * 8]);
            bfr[f] = *reinterpret_cast<const bf16x8*>(&Bs[wn * 64 + f * 16 + lr][lg * 8]);
        }
#pragma unroll
        for (int i = 0; i < 4; ++i)
#pragma unroll
            for (int j = 0; j < 4; ++j)
                acc[i][j] = __builtin_amdgcn_mfma_f32_16x16x32_bf16(af[i], bfr[j], acc[i][j], 0, 0, 0);
    }

#pragma unroll
    for (int i = 0; i < 4; ++i) {
#pragma unroll
        for (int j = 0; j < 4; ++j) {
            int col = n0 + wn * 64 + j * 16 + lr;
            if (NEDGE && col >= N) continue;
            float bv = BIAS ? bias[col] : 0.0f;
#pragma unroll
            for (int r = 0; r < 4; ++r) {
                int row = m0 + wm * 64 + i * 16 + lg * 4 + r;
                float v = acc[i][j][r] + bv;
                if (ACT == 1) v = 0.5f * v * (1.0f + erff(v * 0.70710678118654752f));
                if (RESID) v += resid[(size_t)row * ldc + col];
                if (OUTBF16)
                    reinterpret_cast<unsigned short*>(Cout)[(size_t)row * ldc + col] = f2bf(v);
                else
                    reinterpret_cast<float*>(Cout)[(size_t)row * ldc + col] = v;
            }
        }
    }
}

// ---------------- V transpose: qkv v-part [t][d] -> vt[b][h][d][t] (bf16)
__global__ __launch_bounds__(256) void vtrans_kernel(
    const unsigned short* __restrict__ qkv, unsigned short* __restrict__ vt) {
    __shared__ unsigned short tile[32][33];
    int bh = blockIdx.z; int b = bh >> 4, h = bh & 15;
    int t0 = blockIdx.x * 32, d0 = blockIdx.y * 32;
    int tx = threadIdx.x, ty = threadIdx.y;  // (32,8)
#pragma unroll
    for (int i = 0; i < 4; ++i)
        tile[ty + i * 8][tx] =
            qkv[(size_t)(b * NT + t0 + ty + i * 8) * 3072 + 2048 + h * 64 + d0 + tx];
    __syncthreads();
#pragma unroll
    for (int i = 0; i < 4; ++i)
        vt[((size_t)(b * NH + h) * 64 + d0 + ty + i * 8) * NT + t0 + tx] = tile[tx][ty + i * 8];
}

// ---------------- causal flash attention: 1 wave per (b, h, 32 q-rows)
__global__ __launch_bounds__(64) void attn_kernel(
    const unsigned short* __restrict__ qkv, const unsigned short* __restrict__ vt,
    unsigned short* __restrict__ o) {
    __shared__ unsigned short Vs[64][72];
    __shared__ unsigned short Ps[32][72];
    const int qt = blockIdx.x;   // 0..31
    const int h  = blockIdx.y;   // 0..15
    const int b  = blockIdx.z;   // 0..1
    const int lane = threadIdx.x;
    const int lr = lane & 15, lg = lane >> 4;

    const unsigned short* qbase = qkv + (size_t)(b * NT + qt * 32) * 3072 + h * 64;
    bf16x8 qf[2][2];
#pragma unroll
    for (int mf = 0; mf < 2; ++mf)
#pragma unroll
        for (int kc = 0; kc < 2; ++kc)
            qf[mf][kc] = *reinterpret_cast<const bf16x8*>(
                qbase + (size_t)(mf * 16 + lr) * 3072 + kc * 32 + lg * 8);

    const f32x4 zero4 = {0.0f, 0.0f, 0.0f, 0.0f};
    f32x4 oacc[2][4];
    float mrow[2][4], lsum[2][4];
#pragma unroll
    for (int mf = 0; mf < 2; ++mf) {
#pragma unroll
        for (int nf = 0; nf < 4; ++nf) oacc[mf][nf] = zero4;
#pragma unroll
        for (int r = 0; r < 4; ++r) { mrow[mf][r] = -INFINITY; lsum[mf][r] = 0.0f; }
    }

    const int qend = qt * 32 + 32;
    const int nkt = (qend + 63) >> 6;
    const unsigned short* kbase = qkv + (size_t)(b * NT) * 3072 + NC + h * 64;
    const unsigned short* vbase = vt + (size_t)((b * NH + h) * 64) * NT;

    for (int kt = 0; kt < nkt; ++kt) {
        __syncthreads();   // protect Vs/Ps WAR vs previous iteration
#pragma unroll
        for (int i = 0; i < 8; ++i) {
            int chunk = lane + i * 64;       // 0..511
            int d = chunk >> 3;
            int kk = (chunk & 7) * 8;
            *reinterpret_cast<bf16x8*>(&Vs[d][kk]) =
                *reinterpret_cast<const bf16x8*>(vbase + (size_t)d * NT + kt * 64 + kk);
        }
        // S = Q K^T (K-frags straight from global)
        f32x4 s[2][4];
#pragma unroll
        for (int mf = 0; mf < 2; ++mf)
#pragma unroll
            for (int jf = 0; jf < 4; ++jf) s[mf][jf] = zero4;
#pragma unroll
        for (int kc = 0; kc < 2; ++kc) {
            bf16x8 kf[4];
#pragma unroll
            for (int jf = 0; jf < 4; ++jf)
                kf[jf] = *reinterpret_cast<const bf16x8*>(
                    kbase + (size_t)(kt * 64 + jf * 16 + lr) * 3072 + kc * 32 + lg * 8);
#pragma unroll
            for (int mf = 0; mf < 2; ++mf)
#pragma unroll
                for (int jf = 0; jf < 4; ++jf)
                    s[mf][jf] = __builtin_amdgcn_mfma_f32_16x16x32_bf16(
                        qf[mf][kc], kf[jf], s[mf][jf], 0, 0, 0);
        }
        const bool lastt = (kt == nkt - 1);
        // scale + causal mask + online softmax (rows live across 16-lane groups)
#pragma unroll
        for (int mf = 0; mf < 2; ++mf) {
#pragma unroll
            for (int r = 0; r < 4; ++r) {
                int rowg = qt * 32 + mf * 16 + lg * 4 + r;
                float tmax = -INFINITY;
#pragma unroll
                for (int jf = 0; jf < 4; ++jf) {
                    float v = s[mf][jf][r] * 0.125f;
                    if (lastt) {
                        int colg = kt * 64 + jf * 16 + lr;
                        if (colg > rowg) v = -INFINITY;
                    }
                    s[mf][jf][r] = v;
                    tmax = fmaxf(tmax, v);
                }
                tmax = fmaxf(tmax, __shfl_xor(tmax, 1, 64));
                tmax = fmaxf(tmax, __shfl_xor(tmax, 2, 64));
                tmax = fmaxf(tmax, __shfl_xor(tmax, 4, 64));
                tmax = fmaxf(tmax, __shfl_xor(tmax, 8, 64));
                float mnew = fmaxf(mrow[mf][r], tmax);
                float corr = __expf(mrow[mf][r] - mnew);
                float ps = 0.0f;
#pragma unroll
                for (int jf = 0; jf < 4; ++jf) {
                    float p = __expf(s[mf][jf][r] - mnew);
                    s[mf][jf][r] = p;
                    ps += p;
                }
                ps += __shfl_xor(ps, 1, 64);
                ps += __shfl_xor(ps, 2, 64);
                ps += __shfl_xor(ps, 4, 64);
                ps += __shfl_xor(ps, 8, 64);
                lsum[mf][r] = lsum[mf][r] * corr + ps;
                mrow[mf][r] = mnew;
#pragma unroll
                for (int nf = 0; nf < 4; ++nf) oacc[mf][nf][r] *= corr;
            }
        }
        // P -> LDS (re-layout for PV A-operand)
#pragma unroll
        for (int mf = 0; mf < 2; ++mf)
#pragma unroll
            for (int jf = 0; jf < 4; ++jf)
#pragma unroll
                for (int r = 0; r < 4; ++r)
                    Ps[mf * 16 + lg * 4 + r][jf * 16 + lr] = f2bf(s[mf][jf][r]);
        __syncthreads();
        // O += P V
#pragma unroll
        for (int kc = 0; kc < 2; ++kc) {
            bf16x8 pf[2], vf[4];
#pragma unroll
            for (int mf = 0; mf < 2; ++mf)
                pf[mf] = *reinterpret_cast<const bf16x8*>(&Ps[mf * 16 + lr][kc * 32 + lg * 8]);
#pragma unroll
            for (int nf = 0; nf < 4; ++nf)
                vf[nf] = *reinterpret_cast<const bf16x8*>(&Vs[nf * 16 + lr][kc * 32 + lg * 8]);
#pragma unroll
            for (int mf = 0; mf < 2; ++mf)
#pragma unroll
                for (int nf = 0; nf < 4; ++nf)
                    oacc[mf][nf] = __builtin_amdgcn_mfma_f32_16x16x32_bf16(
                        pf[mf], vf[nf], oacc[mf][nf], 0, 0, 0);
        }
    }

    unsigned short* ob = o + (size_t)(b * NT + qt * 32) * NC + h * 64;
#pragma unroll
    for (int mf = 0; mf < 2; ++mf)
#pragma unroll
        for (int nf = 0; nf < 4; ++nf)
#pragma unroll
            for (int r = 0; r < 4; ++r) {
                float v = oacc[mf][nf][r] / lsum[mf][r];
                ob[(size_t)(mf * 16 + lg * 4 + r) * NC + nf * 16 + lr] = f2bf(v);
            }
}

extern "C" void kernel_launch(void* const* d_in, const int* in_sizes, int n_in,
                              void* d_out, int out_size, void* d_ws, size_t ws_size,
                              hipStream_t stream) {
    (void)in_sizes; (void)n_in; (void)out_size; (void)ws_size;
    const int*   idx    = (const int*)  d_in[0];
    const float* tok    = (const float*)d_in[1];
    const float* pos    = (const float*)d_in[2];
    const float* qkv_w  = (const float*)d_in[3];
    const float* qkv_b  = (const float*)d_in[4];
    const float* out_w  = (const float*)d_in[5];
    const float* out_b  = (const float*)d_in[6];
    const float* ln1_s  = (const float*)d_in[7];
    const float* ln1_b  = (const float*)d_in[8];
    const float* ln2_s  = (const float*)d_in[9];
    const float* ln2_b  = (const float*)d_in[10];
    const float* ffn_w1 = (const float*)d_in[11];
    const float* ffn_b1 = (const float*)d_in[12];
    const float* ffn_w2 = (const float*)d_in[13];
    const float* ffn_b2 = (const float*)d_in[14];
    const float* lnf_s  = (const float*)d_in[15];
    const float* lnf_b  = (const float*)d_in[16];

    char* p = (char*)d_ws;
    float* x              = (float*)p;          p += (size_t)NM * NC * 4;
    unsigned short* hbuf  = (unsigned short*)p; p += (size_t)NM * NC * 2;
    unsigned short* qkvb  = (unsigned short*)p; p += (size_t)NM * 3 * NC * 2;
    unsigned short* obuf  = (unsigned short*)p; p += (size_t)NM * NC * 2;
    unsigned short* gbuf  = (unsigned short*)p; p += (size_t)NM * NFF * 2;
    unsigned short* vtb   = (unsigned short*)p; p += (size_t)NB * NH * 64 * NT * 2;
    unsigned short* wq    = (unsigned short*)p; p += (size_t)3 * NC * NC * 2;
    unsigned short* wo    = (unsigned short*)p; p += (size_t)NC * NC * 2;
    unsigned short* w1    = (unsigned short*)p; p += (size_t)NC * NFF * 2;
    unsigned short* w2    = (unsigned short*)p; p += (size_t)NFF * NC * 2;
    unsigned short* temb  = (unsigned short*)p; p += (size_t)NV * NC * 2;

    // tok_emb -> bf16 (reused by tied head)
    {
        size_t n4 = (size_t)NV * NC / 4;
        int blocks = (int)((n4 + 255) / 256);
        cvt_bf16_kernel<<<blocks, 256, 0, stream>>>(tok, temb, n4);
    }
    embed_kernel<<<NM, 256, 0, stream>>>(idx, tok, pos, x);

    for (int l = 0; l < NL; ++l) {
        wtrans_kernel<<<dim3(96, 32),  dim3(32, 8), 0, stream>>>(qkv_w + (size_t)l * NC * 3 * NC, wq, NC, 3 * NC);
        wtrans_kernel<<<dim3(32, 32),  dim3(32, 8), 0, stream>>>(out_w + (size_t)l * NC * NC, wo, NC, NC);
        wtrans_kernel<<<dim3(128, 32), dim3(32, 8), 0, stream>>>(ffn_w1 + (size_t)l * NC * NFF, w1, NC, NFF);
        wtrans_kernel<<<dim3(32, 128), dim3(32, 8), 0, stream>>>(ffn_w2 + (size_t)l * NFF * NC, w2, NFF, NC);

        ln_kernel<<<NM, 256, 0, stream>>>(x, ln1_s + (size_t)l * NC, ln1_b + (size_t)l * NC, hbuf);
        gemm_kernel<0, true, false, true, false><<<dim3(24, 16), 256, 0, stream>>>(
            hbuf, wq, qkv_b + (size_t)l * 3 * NC, nullptr, qkvb, 3 * NC, NC, 3 * NC);
        vtrans_kernel<<<dim3(32, 2, 32), dim3(32, 8), 0, stream>>>(qkvb, vtb);
        attn_kernel<<<dim3(32, 16, 2), 64, 0, stream>>>(qkvb, vtb, obuf);
        gemm_kernel<0, true, true, false, false><<<dim3(8, 16), 256, 0, stream>>>(
            obuf, wo, out_b + (size_t)l * NC, x, x, NC, NC, NC);
        ln_kernel<<<NM, 256, 0, stream>>>(x, ln2_s + (size_t)l * NC, ln2_b + (size_t)l * NC, hbuf);
        gemm_kernel<1, true, false, true, false><<<dim3(32, 16), 256, 0, stream>>>(
            hbuf, w1, ffn_b1 + (size_t)l * NFF, nullptr, gbuf, NFF, NC, NFF);
        gemm_kernel<0, true, true, false, false><<<dim3(8, 16), 256, 0, stream>>>(
            gbuf, w2, ffn_b2 + (size_t)l * NC, x, x, NC, NFF, NC);
    }
    ln_kernel<<<NM, 256, 0, stream>>>(x, lnf_s, lnf_b, hbuf);
    gemm_kernel<0, false, false, false, true><<<dim3(393, 16), 256, 0, stream>>>(
        hbuf, temb, nullptr, nullptr, d_out, NV, NC, NV);
}

// Round 2
// 2258.631 us; speedup vs baseline: 1.1310x; 1.1310x over previous
//
#include <hip/hip_runtime.h>
#include <hip/hip_bf16.h>

#define NL 8
#define NV 50257
#define NC 1024
#define NH 16
#define NT 1024
#define NFF 4096
#define NB 2
#define NM (NB*NT)   // 2048 rows

typedef __attribute__((ext_vector_type(8))) short bf16x8;
typedef __attribute__((ext_vector_type(4))) float f32x4;

__device__ __forceinline__ unsigned short f2bf(float f) {
    union { float f; unsigned u; } a; a.f = f;
    unsigned r = a.u + 0x7FFFu + ((a.u >> 16) & 1u);
    return (unsigned short)(r >> 16);
}

__device__ __forceinline__ void gload16(const unsigned short* g, unsigned short* l) {
    __builtin_amdgcn_global_load_lds(
        (const __attribute__((address_space(1))) unsigned int*)g,
        (__attribute__((address_space(3))) unsigned int*)l,
        16, 0, 0);
}

// ---------------- embedding: x[b,t,:] = tok_emb[idx[b,t],:] + pos_emb[t,:]
__global__ __launch_bounds__(256) void embed_kernel(
    const int* __restrict__ idx, const float* __restrict__ te,
    const float* __restrict__ pe, float* __restrict__ x) {
    int row = blockIdx.x;            // 0..2047 = b*1024 + t
    int t = row & (NT - 1);
    int id = idx[row];
    const float4 a = reinterpret_cast<const float4*>(te + (size_t)id * NC)[threadIdx.x];
    const float4 b = reinterpret_cast<const float4*>(pe + (size_t)t * NC)[threadIdx.x];
    float4 o; o.x = a.x + b.x; o.y = a.y + b.y; o.z = a.z + b.z; o.w = a.w + b.w;
    reinterpret_cast<float4*>(x + (size_t)row * NC)[threadIdx.x] = o;
}

// ---------------- f32 -> bf16 bulk convert (tok_emb)
__global__ __launch_bounds__(256) void cvt_bf16_kernel(
    const float* __restrict__ in, unsigned short* __restrict__ out, size_t n4) {
    size_t i = (size_t)blockIdx.x * 256 + threadIdx.x;
    if (i >= n4) return;
    float4 v = reinterpret_cast<const float4*>(in)[i];
    uint2 u;
    u.x = (unsigned)f2bf(v.x) | ((unsigned)f2bf(v.y) << 16);
    u.y = (unsigned)f2bf(v.z) | ((unsigned)f2bf(v.w) << 16);
    reinterpret_cast<uint2*>(out)[i] = u;
}

// ---------------- weight transpose+convert: W[K][N] f32 -> Wt[N][K] bf16
__global__ __launch_bounds__(256) void wtrans_kernel(
    const float* __restrict__ W, unsigned short* __restrict__ Wt, int K, int N) {
    __shared__ float tile[32][33];
    int n0 = blockIdx.x * 32, k0 = blockIdx.y * 32;
    int tx = threadIdx.x, ty = threadIdx.y;  // (32,8)
#pragma unroll
    for (int i = 0; i < 4; ++i)
        tile[ty + i * 8][tx] = W[(size_t)(k0 + ty + i * 8) * N + n0 + tx];
    __syncthreads();
#pragma unroll
    for (int i = 0; i < 4; ++i)
        Wt[(size_t)(n0 + ty + i * 8) * K + k0 + tx] = f2bf(tile[tx][ty + i * 8]);
}

// ---------------- layernorm (f32 in -> bf16 out), one block per row, C=1024
__global__ __launch_bounds__(256) void ln_kernel(
    const float* __restrict__ x, const float* __restrict__ gam,
    const float* __restrict__ bet, unsigned short* __restrict__ out) {
    __shared__ float red[4];
    int row = blockIdx.x, tid = threadIdx.x;
    const float4 v = reinterpret_cast<const float4*>(x + (size_t)row * NC)[tid];
    float s = v.x + v.y + v.z + v.w;
#pragma unroll
    for (int m = 32; m >= 1; m >>= 1) s += __shfl_xor(s, m, 64);
    if ((tid & 63) == 0) red[tid >> 6] = s;
    __syncthreads();
    float mean = (red[0] + red[1] + red[2] + red[3]) * (1.0f / NC);
    __syncthreads();
    float dx = v.x - mean, dy = v.y - mean, dz = v.z - mean, dw = v.w - mean;
    float q = dx * dx + dy * dy + dz * dz + dw * dw;
#pragma unroll
    for (int m = 32; m >= 1; m >>= 1) q += __shfl_xor(q, m, 64);
    if ((tid & 63) == 0) red[tid >> 6] = q;
    __syncthreads();
    float var = (red[0] + red[1] + red[2] + red[3]) * (1.0f / NC);
    float rstd = rsqrtf(var + 1e-5f);
    int c = tid * 4;
    const float4 g4 = reinterpret_cast<const float4*>(gam)[tid];
    const float4 b4 = reinterpret_cast<const float4*>(bet)[tid];
    uint2 u;
    u.x = (unsigned)f2bf(dx * rstd * g4.x + b4.x) |
          ((unsigned)f2bf(dy * rstd * g4.y + b4.y) << 16);
    u.y = (unsigned)f2bf(dz * rstd * g4.z + b4.z) |
          ((unsigned)f2bf(dw * rstd * g4.w + b4.w) << 16);
    reinterpret_cast<uint2*>(out + (size_t)row * NC + c)[0] = u;
}

// ---------------- GEMM: C[M][N] = A[M][K](bf16) * Bt[N][K](bf16)^T
// m97 structure: 128x128 tile, BK=32, linear LDS, global_load_lds width-16.
// grid: x = M-tiles (fast axis, shares B-panel in L2/L3), y = N-tiles,
//       z = K-splits (ATOMIC accumulates into Cout which already holds resid).
template<int ACT, bool BIAS, bool OUTBF16, bool NEDGE, bool ATOMIC>
__global__ __launch_bounds__(256) void gemm_kernel(
    const unsigned short* __restrict__ A, const unsigned short* __restrict__ Bt,
    const float* __restrict__ bias, void* __restrict__ Cout,
    int N, int K, int ldc, int ksub) {
    __shared__ unsigned short As[128 * 32];
    __shared__ unsigned short Bs[128 * 32];
    const int tid = threadIdx.x;
    const int lane = tid & 63;
    const int wave = tid >> 6;
    const int wm = wave >> 1, wn = wave & 1;
    const int lr = lane & 15, lg = lane >> 4;
    const int m0 = blockIdx.x * 128, n0 = blockIdx.y * 128;
    const int kbeg = blockIdx.z * ksub, kend = kbeg + ksub;

    const int r0 = tid >> 2;            // staging row within 64-row half
    const int c0 = (tid & 3) * 8;       // staging col (elements)
    int bn0 = n0 + r0, bn1 = n0 + r0 + 64;
    if (NEDGE) { bn0 = min(bn0, N - 1); bn1 = min(bn1, N - 1); }
    const unsigned short* Ag0 = A + (size_t)(m0 + r0) * K + c0;
    const unsigned short* Ag1 = A + (size_t)(m0 + r0 + 64) * K + c0;
    const unsigned short* Bg0 = Bt + (size_t)bn0 * K + c0;
    const unsigned short* Bg1 = Bt + (size_t)bn1 * K + c0;
    unsigned short* Al0 = As + wave * 512;          // bytes: wave*1024
    unsigned short* Al1 = As + 2048 + wave * 512;   // +4096B
    unsigned short* Bl0 = Bs + wave * 512;
    unsigned short* Bl1 = Bs + 2048 + wave * 512;

    const f32x4 zero4 = {0.0f, 0.0f, 0.0f, 0.0f};
    f32x4 acc[4][4];
#pragma unroll
    for (int i = 0; i < 4; ++i)
#pragma unroll
        for (int j = 0; j < 4; ++j) acc[i][j] = zero4;

    for (int k0 = kbeg; k0 < kend; k0 += 32) {
        __syncthreads();
        gload16(Ag0 + k0, Al0);
        gload16(Ag1 + k0, Al1);
        gload16(Bg0 + k0, Bl0);
        gload16(Bg1 + k0, Bl1);
        __syncthreads();   // compiler drains vmcnt before s_barrier
        bf16x8 af[4], bfr[4];
#pragma unroll
        for (int f = 0; f < 4; ++f) {
            af[f]  = *reinterpret_cast<const bf16x8*>(As + (wm * 64 + f * 16 + lr) * 32 + lg * 8);
            bfr[f] = *reinterpret_cast<const bf16x8*>(Bs + (wn * 64 + f * 16 + lr) * 32 + lg * 8);
        }
#pragma unroll
        for (int i = 0; i < 4; ++i)
#pragma unroll
            for (int j = 0; j < 4; ++j)
                acc[i][j] = __builtin_amdgcn_mfma_f32_16x16x32_bf16(af[i], bfr[j], acc[i][j], 0, 0, 0);
    }

#pragma unroll
    for (int i = 0; i < 4; ++i) {
#pragma unroll
        for (int j = 0; j < 4; ++j) {
            int col = n0 + wn * 64 + j * 16 + lr;
            if (NEDGE && col >= N) continue;
            float bv = (BIAS && kbeg == 0) ? bias[col] : 0.0f;
#pragma unroll
            for (int r = 0; r < 4; ++r) {
                int row = m0 + wm * 64 + i * 16 + lg * 4 + r;
                float v = acc[i][j][r] + bv;
                if (ACT == 1) v = 0.5f * v * (1.0f + erff(v * 0.70710678118654752f));
                if (ATOMIC) {
                    atomicAdd(reinterpret_cast<float*>(Cout) + (size_t)row * ldc + col, v);
                } else if (OUTBF16) {
                    reinterpret_cast<unsigned short*>(Cout)[(size_t)row * ldc + col] = f2bf(v);
                } else {
                    reinterpret_cast<float*>(Cout)[(size_t)row * ldc + col] = v;
                }
            }
        }
    }
}

// ---------------- V transpose: qkv v-part [t][d] -> vt[b][h][d][t] (bf16)
__global__ __launch_bounds__(256) void vtrans_kernel(
    const unsigned short* __restrict__ qkv, unsigned short* __restrict__ vt) {
    __shared__ unsigned short tile[32][33];
    int bh = blockIdx.z; int b = bh >> 4, h = bh & 15;
    int t0 = blockIdx.x * 32, d0 = blockIdx.y * 32;
    int tx = threadIdx.x, ty = threadIdx.y;  // (32,8)
#pragma unroll
    for (int i = 0; i < 4; ++i)
        tile[ty + i * 8][tx] =
            qkv[(size_t)(b * NT + t0 + ty + i * 8) * 3072 + 2048 + h * 64 + d0 + tx];
    __syncthreads();
#pragma unroll
    for (int i = 0; i < 4; ++i)
        vt[((size_t)(b * NH + h) * 64 + d0 + ty + i * 8) * NT + t0 + tx] = tile[tx][ty + i * 8];
}

// ---------------- causal flash attention: 1 wave per (b, h, 32 q-rows)
__global__ __launch_bounds__(64) void attn_kernel(
    const unsigned short* __restrict__ qkv, const unsigned short* __restrict__ vt,
    unsigned short* __restrict__ o) {
    __shared__ unsigned short Vs[64][72];
    __shared__ unsigned short Ps[32][72];
    const int qt = blockIdx.x;   // 0..31
    const int h  = blockIdx.y;   // 0..15
    const int b  = blockIdx.z;   // 0..1
    const int lane = threadIdx.x;
    const int lr = lane & 15, lg = lane >> 4;

    const unsigned short* qbase = qkv + (size_t)(b * NT + qt * 32) * 3072 + h * 64;
    bf16x8 qf[2][2];
#pragma unroll
    for (int mf = 0; mf < 2; ++mf)
#pragma unroll
        for (int kc = 0; kc < 2; ++kc)
            qf[mf][kc] = *reinterpret_cast<const bf16x8*>(
                qbase + (size_t)(mf * 16 + lr) * 3072 + kc * 32 + lg * 8);

    const f32x4 zero4 = {0.0f, 0.0f, 0.0f, 0.0f};
    f32x4 oacc[2][4];
    float mrow[2][4], lsum[2][4];
#pragma unroll
    for (int mf = 0; mf < 2; ++mf) {
#pragma unroll
        for (int nf = 0; nf < 4; ++nf) oacc[mf][nf] = zero4;
#pragma unroll
        for (int r = 0; r < 4; ++r) { mrow[mf][r] = -INFINITY; lsum[mf][r] = 0.0f; }
    }

    const int qend = qt * 32 + 32;
    const int nkt = (qend + 63) >> 6;
    const unsigned short* kbase = qkv + (size_t)(b * NT) * 3072 + NC + h * 64;
    const unsigned short* vbase = vt + (size_t)((b * NH + h) * 64) * NT;

    for (int kt = 0; kt < nkt; ++kt) {
        __syncthreads();   // protect Vs/Ps WAR vs previous iteration
#pragma unroll
        for (int i = 0; i < 8; ++i) {
            int chunk = lane + i * 64;       // 0..511
            int d = chunk >> 3;
            int kk = (chunk & 7) * 8;
            *reinterpret_cast<bf16x8*>(&Vs[d][kk]) =
                *reinterpret_cast<const bf16x8*>(vbase + (size_t)d * NT + kt * 64 + kk);
        }
        // S = Q K^T (K-frags straight from global)
        f32x4 s[2][4];
#pragma unroll
        for (int mf = 0; mf < 2; ++mf)
#pragma unroll
            for (int jf = 0; jf < 4; ++jf) s[mf][jf] = zero4;
#pragma unroll
        for (int kc = 0; kc < 2; ++kc) {
            bf16x8 kf[4];
#pragma unroll
            for (int jf = 0; jf < 4; ++jf)
                kf[jf] = *reinterpret_cast<const bf16x8*>(
                    kbase + (size_t)(kt * 64 + jf * 16 + lr) * 3072 + kc * 32 + lg * 8);
#pragma unroll
            for (int mf = 0; mf < 2; ++mf)
#pragma unroll
                for (int jf = 0; jf < 4; ++jf)
                    s[mf][jf] = __builtin_amdgcn_mfma_f32_16x16x32_bf16(
                        qf[mf][kc], kf[jf], s[mf][jf], 0, 0, 0);
        }
        const bool lastt = (kt == nkt - 1);
        // scale + causal mask + online softmax (rows live across 16-lane groups)
#pragma unroll
        for (int mf = 0; mf < 2; ++mf) {
#pragma unroll
            for (int r = 0; r < 4; ++r) {
                int rowg = qt * 32 + mf * 16 + lg * 4 + r;
                float tmax = -INFINITY;
#pragma unroll
                for (int jf = 0; jf < 4; ++jf) {
                    float v = s[mf][jf][r] * 0.125f;
                    if (lastt) {
                        int colg = kt * 64 + jf * 16 + lr;
                        if (colg > rowg) v = -INFINITY;
                    }
                    s[mf][jf][r] = v;
                    tmax = fmaxf(tmax, v);
                }
                tmax = fmaxf(tmax, __shfl_xor(tmax, 1, 64));
                tmax = fmaxf(tmax, __shfl_xor(tmax, 2, 64));
                tmax = fmaxf(tmax, __shfl_xor(tmax, 4, 64));
                tmax = fmaxf(tmax, __shfl_xor(tmax, 8, 64));
                float mnew = fmaxf(mrow[mf][r], tmax);
                float corr = __expf(mrow[mf][r] - mnew);
                float ps = 0.0f;
#pragma unroll
                for (int jf = 0; jf < 4; ++jf) {
                    float p = __expf(s[mf][jf][r] - mnew);
                    s[mf][jf][r] = p;
                    ps += p;
                }
                ps += __shfl_xor(ps, 1, 64);
                ps += __shfl_xor(ps, 2, 64);
                ps += __shfl_xor(ps, 4, 64);
                ps += __shfl_xor(ps, 8, 64);
                lsum[mf][r] = lsum[mf][r] * corr + ps;
                mrow[mf][r] = mnew;
#pragma unroll
                for (int nf = 0; nf < 4; ++nf) oacc[mf][nf][r] *= corr;
            }
        }
        // P -> LDS (re-layout for PV A-operand)
#pragma unroll
        for (int mf = 0; mf < 2; ++mf)
#pragma unroll
            for (int jf = 0; jf < 4; ++jf)
#pragma unroll
                for (int r = 0; r < 4; ++r)
                    Ps[mf * 16 + lg * 4 + r][jf * 16 + lr] = f2bf(s[mf][jf][r]);
        __syncthreads();
        // O += P V
#pragma unroll
        for (int kc = 0; kc < 2; ++kc) {
            bf16x8 pf[2], vf[4];
#pragma unroll
            for (int mf = 0; mf < 2; ++mf)
                pf[mf] = *reinterpret_cast<const bf16x8*>(&Ps[mf * 16 + lr][kc * 32 + lg * 8]);
#pragma unroll
            for (int nf = 0; nf < 4; ++nf)
                vf[nf] = *reinterpret_cast<const bf16x8*>(&Vs[nf * 16 + lr][kc * 32 + lg * 8]);
#pragma unroll
            for (int mf = 0; mf < 2; ++mf)
#pragma unroll
                for (int nf = 0; nf < 4; ++nf)
                    oacc[mf][nf] = __builtin_amdgcn_mfma_f32_16x16x32_bf16(
                        pf[mf], vf[nf], oacc[mf][nf], 0, 0, 0);
        }
    }

    unsigned short* ob = o + (size_t)(b * NT + qt * 32) * NC + h * 64;
#pragma unroll
    for (int mf = 0; mf < 2; ++mf)
#pragma unroll
        for (int nf = 0; nf < 4; ++nf)
#pragma unroll
            for (int r = 0; r < 4; ++r) {
                float v = oacc[mf][nf][r] / lsum[mf][r];
                ob[(size_t)(mf * 16 + lg * 4 + r) * NC + nf * 16 + lr] = f2bf(v);
            }
}

extern "C" void kernel_launch(void* const* d_in, const int* in_sizes, int n_in,
                              void* d_out, int out_size, void* d_ws, size_t ws_size,
                              hipStream_t stream) {
    (void)in_sizes; (void)n_in; (void)out_size; (void)ws_size;
    const int*   idx    = (const int*)  d_in[0];
    const float* tok    = (const float*)d_in[1];
    const float* pos    = (const float*)d_in[2];
    const float* qkv_w  = (const float*)d_in[3];
    const float* qkv_b  = (const float*)d_in[4];
    const float* out_w  = (const float*)d_in[5];
    const float* out_b  = (const float*)d_in[6];
    const float* ln1_s  = (const float*)d_in[7];
    const float* ln1_b  = (const float*)d_in[8];
    const float* ln2_s  = (const float*)d_in[9];
    const float* ln2_b  = (const float*)d_in[10];
    const float* ffn_w1 = (const float*)d_in[11];
    const float* ffn_b1 = (const float*)d_in[12];
    const float* ffn_w2 = (const float*)d_in[13];
    const float* ffn_b2 = (const float*)d_in[14];
    const float* lnf_s  = (const float*)d_in[15];
    const float* lnf_b  = (const float*)d_in[16];

    char* p = (char*)d_ws;
    float* x              = (float*)p;          p += (size_t)NM * NC * 4;
    unsigned short* hbuf  = (unsigned short*)p; p += (size_t)NM * NC * 2;
    unsigned short* qkvb  = (unsigned short*)p; p += (size_t)NM * 3 * NC * 2;
    unsigned short* obuf  = (unsigned short*)p; p += (size_t)NM * NC * 2;
    unsigned short* gbuf  = (unsigned short*)p; p += (size_t)NM * NFF * 2;
    unsigned short* vtb   = (unsigned short*)p; p += (size_t)NB * NH * 64 * NT * 2;
    unsigned short* wq    = (unsigned short*)p; p += (size_t)3 * NC * NC * 2;
    unsigned short* wo    = (unsigned short*)p; p += (size_t)NC * NC * 2;
    unsigned short* w1    = (unsigned short*)p; p += (size_t)NC * NFF * 2;
    unsigned short* w2    = (unsigned short*)p; p += (size_t)NFF * NC * 2;
    unsigned short* temb  = (unsigned short*)p; p += (size_t)NV * NC * 2;

    // tok_emb -> bf16 (reused by tied head)
    {
        size_t n4 = (size_t)NV * NC / 4;
        int blocks = (int)((n4 + 255) / 256);
        cvt_bf16_kernel<<<blocks, 256, 0, stream>>>(tok, temb, n4);
    }
    embed_kernel<<<NM, 256, 0, stream>>>(idx, tok, pos, x);

    for (int l = 0; l < NL; ++l) {
        wtrans_kernel<<<dim3(96, 32),  dim3(32, 8), 0, stream>>>(qkv_w + (size_t)l * NC * 3 * NC, wq, NC, 3 * NC);
        wtrans_kernel<<<dim3(32, 32),  dim3(32, 8), 0, stream>>>(out_w + (size_t)l * NC * NC, wo, NC, NC);
        wtrans_kernel<<<dim3(128, 32), dim3(32, 8), 0, stream>>>(ffn_w1 + (size_t)l * NC * NFF, w1, NC, NFF);
        wtrans_kernel<<<dim3(32, 128), dim3(32, 8), 0, stream>>>(ffn_w2 + (size_t)l * NFF * NC, w2, NFF, NC);

        ln_kernel<<<NM, 256, 0, stream>>>(x, ln1_s + (size_t)l * NC, ln1_b + (size_t)l * NC, hbuf);
        // qkv: [2048 x 3072] = hbuf @ wq^T
        gemm_kernel<0, true, true, false, false><<<dim3(16, 24), 256, 0, stream>>>(
            hbuf, wq, qkv_b + (size_t)l * 3 * NC, qkvb, 3 * NC, NC, 3 * NC, NC);
        vtrans_kernel<<<dim3(32, 2, 32), dim3(32, 8), 0, stream>>>(qkvb, vtb);
        attn_kernel<<<dim3(32, 16, 2), 64, 0, stream>>>(qkvb, vtb, obuf);
        // proj: x += obuf @ wo^T + b   (split-K=2, atomic into resident x)
        gemm_kernel<0, true, false, false, true><<<dim3(16, 8, 2), 256, 0, stream>>>(
            obuf, wo, out_b + (size_t)l * NC, x, NC, NC, NC, NC / 2);
        ln_kernel<<<NM, 256, 0, stream>>>(x, ln2_s + (size_t)l * NC, ln2_b + (size_t)l * NC, hbuf);
        // ffn1 + gelu
        gemm_kernel<1, true, true, false, false><<<dim3(16, 32), 256, 0, stream>>>(
            hbuf, w1, ffn_b1 + (size_t)l * NFF, gbuf, NFF, NC, NFF, NC);
        // ffn2: x += gbuf @ w2^T + b   (split-K=4, atomic into resident x)
        gemm_kernel<0, true, false, false, true><<<dim3(16, 8, 4), 256, 0, stream>>>(
            gbuf, w2, ffn_b2 + (size_t)l * NC, x, NC, NFF, NC, NFF / 4);
    }
    ln_kernel<<<NM, 256, 0, stream>>>(x, lnf_s, lnf_b, hbuf);
    // tied head: [2048 x 50257], M-tiles on fast axis for temb L2/L3 reuse
    gemm_kernel<0, false, false, true, false><<<dim3(16, 393), 256, 0, stream>>>(
        hbuf, temb, nullptr, d_out, NV, NC, NV, NC);
}

// Round 3
// 2220.451 us; speedup vs baseline: 1.1505x; 1.0172x over previous
//
#include <hip/hip_runtime.h>
#include <hip/hip_bf16.h>

#define NL 8
#define NV 50257
#define NC 1024
#define NH 16
#define NT 1024
#define NFF 4096
#define NB 2
#define NM (NB*NT)   // 2048 rows

typedef __attribute__((ext_vector_type(8))) short bf16x8;
typedef __attribute__((ext_vector_type(4))) float f32x4;

__device__ __forceinline__ unsigned short f2bf(float f) {
    union { float f; unsigned u; } a; a.f = f;
    unsigned r = a.u + 0x7FFFu + ((a.u >> 16) & 1u);
    return (unsigned short)(r >> 16);
}

__device__ __forceinline__ void gload16(const unsigned short* g, unsigned short* l) {
    __builtin_amdgcn_global_load_lds(
        (const __attribute__((address_space(1))) unsigned int*)g,
        (__attribute__((address_space(3))) unsigned int*)l,
        16, 0, 0);
}

template<int VN> __device__ __forceinline__ void vwait() {
    asm volatile("s_waitcnt vmcnt(%0)" :: "n"(VN) : "memory");
}
__device__ __forceinline__ void barrier_mem() {
    asm volatile("" ::: "memory");
    __builtin_amdgcn_s_barrier();
    asm volatile("" ::: "memory");
}

// ---------------- embedding: x[b,t,:] = tok_emb[idx[b,t],:] + pos_emb[t,:]
__global__ __launch_bounds__(256) void embed_kernel(
    const int* __restrict__ idx, const float* __restrict__ te,
    const float* __restrict__ pe, float* __restrict__ x) {
    int row = blockIdx.x;            // 0..2047 = b*1024 + t
    int t = row & (NT - 1);
    int id = idx[row];
    const float4 a = reinterpret_cast<const float4*>(te + (size_t)id * NC)[threadIdx.x];
    const float4 b = reinterpret_cast<const float4*>(pe + (size_t)t * NC)[threadIdx.x];
    float4 o; o.x = a.x + b.x; o.y = a.y + b.y; o.z = a.z + b.z; o.w = a.w + b.w;
    reinterpret_cast<float4*>(x + (size_t)row * NC)[threadIdx.x] = o;
}

// ---------------- f32 -> bf16 bulk convert (tok_emb)
__global__ __launch_bounds__(256) void cvt_bf16_kernel(
    const float* __restrict__ in, unsigned short* __restrict__ out, size_t n4) {
    size_t i = (size_t)blockIdx.x * 256 + threadIdx.x;
    if (i >= n4) return;
    float4 v = reinterpret_cast<const float4*>(in)[i];
    uint2 u;
    u.x = (unsigned)f2bf(v.x) | ((unsigned)f2bf(v.y) << 16);
    u.y = (unsigned)f2bf(v.z) | ((unsigned)f2bf(v.w) << 16);
    reinterpret_cast<uint2*>(out)[i] = u;
}

// ---------------- weight transpose+convert: W[K][N] f32 -> Wt[N][K] bf16
__global__ __launch_bounds__(256) void wtrans_kernel(
    const float* __restrict__ W, unsigned short* __restrict__ Wt, int K, int N) {
    __shared__ float tile[32][33];
    int n0 = blockIdx.x * 32, k0 = blockIdx.y * 32;
    int tx = threadIdx.x, ty = threadIdx.y;  // (32,8)
#pragma unroll
    for (int i = 0; i < 4; ++i)
        tile[ty + i * 8][tx] = W[(size_t)(k0 + ty + i * 8) * N + n0 + tx];
    __syncthreads();
#pragma unroll
    for (int i = 0; i < 4; ++i)
        Wt[(size_t)(n0 + ty + i * 8) * K + k0 + tx] = f2bf(tile[tx][ty + i * 8]);
}

// ---------------- layernorm (f32 in -> bf16 out), one block per row, C=1024
__global__ __launch_bounds__(256) void ln_kernel(
    const float* __restrict__ x, const float* __restrict__ gam,
    const float* __restrict__ bet, unsigned short* __restrict__ out) {
    __shared__ float red[4];
    int row = blockIdx.x, tid = threadIdx.x;
    const float4 v = reinterpret_cast<const float4*>(x + (size_t)row * NC)[tid];
    float s = v.x + v.y + v.z + v.w;
#pragma unroll
    for (int m = 32; m >= 1; m >>= 1) s += __shfl_xor(s, m, 64);
    if ((tid & 63) == 0) red[tid >> 6] = s;
    __syncthreads();
    float mean = (red[0] + red[1] + red[2] + red[3]) * (1.0f / NC);
    __syncthreads();
    float dx = v.x - mean, dy = v.y - mean, dz = v.z - mean, dw = v.w - mean;
    float q = dx * dx + dy * dy + dz * dz + dw * dw;
#pragma unroll
    for (int m = 32; m >= 1; m >>= 1) q += __shfl_xor(q, m, 64);
    if ((tid & 63) == 0) red[tid >> 6] = q;
    __syncthreads();
    float var = (red[0] + red[1] + red[2] + red[3]) * (1.0f / NC);
    float rstd = rsqrtf(var + 1e-5f);
    int c = tid * 4;
    const float4 g4 = reinterpret_cast<const float4*>(gam)[tid];
    const float4 b4 = reinterpret_cast<const float4*>(bet)[tid];
    uint2 u;
    u.x = (unsigned)f2bf(dx * rstd * g4.x + b4.x) |
          ((unsigned)f2bf(dy * rstd * g4.y + b4.y) << 16);
    u.y = (unsigned)f2bf(dz * rstd * g4.z + b4.z) |
          ((unsigned)f2bf(dw * rstd * g4.w + b4.w) << 16);
    reinterpret_cast<uint2*>(out + (size_t)row * NC + c)[0] = u;
}

// ---------------- GEMM: C[M][N] = A[M][K](bf16) * Bt[N][K](bf16)^T
// m97 structure: 128x128 tile, BK=32, linear LDS, global_load_lds width-16.
template<int ACT, bool BIAS, bool OUTBF16, bool NEDGE, bool ATOMIC>
__global__ __launch_bounds__(256) void gemm_kernel(
    const unsigned short* __restrict__ A, const unsigned short* __restrict__ Bt,
    const float* __restrict__ bias, void* __restrict__ Cout,
    int N, int K, int ldc, int ksub) {
    __shared__ unsigned short As[128 * 32];
    __shared__ unsigned short Bs[128 * 32];
    const int tid = threadIdx.x;
    const int lane = tid & 63;
    const int wave = tid >> 6;
    const int wm = wave >> 1, wn = wave & 1;
    const int lr = lane & 15, lg = lane >> 4;
    const int m0 = blockIdx.x * 128, n0 = blockIdx.y * 128;
    const int kbeg = blockIdx.z * ksub, kend = kbeg + ksub;

    const int r0 = tid >> 2;            // staging row within 64-row half
    const int c0 = (tid & 3) * 8;       // staging col (elements)
    int bn0 = n0 + r0, bn1 = n0 + r0 + 64;
    if (NEDGE) { bn0 = min(bn0, N - 1); bn1 = min(bn1, N - 1); }
    const unsigned short* Ag0 = A + (size_t)(m0 + r0) * K + c0;
    const unsigned short* Ag1 = A + (size_t)(m0 + r0 + 64) * K + c0;
    const unsigned short* Bg0 = Bt + (size_t)bn0 * K + c0;
    const unsigned short* Bg1 = Bt + (size_t)bn1 * K + c0;
    unsigned short* Al0 = As + wave * 512;
    unsigned short* Al1 = As + 2048 + wave * 512;
    unsigned short* Bl0 = Bs + wave * 512;
    unsigned short* Bl1 = Bs + 2048 + wave * 512;

    const f32x4 zero4 = {0.0f, 0.0f, 0.0f, 0.0f};
    f32x4 acc[4][4];
#pragma unroll
    for (int i = 0; i < 4; ++i)
#pragma unroll
        for (int j = 0; j < 4; ++j) acc[i][j] = zero4;

    for (int k0 = kbeg; k0 < kend; k0 += 32) {
        __syncthreads();
        gload16(Ag0 + k0, Al0);
        gload16(Ag1 + k0, Al1);
        gload16(Bg0 + k0, Bl0);
        gload16(Bg1 + k0, Bl1);
        __syncthreads();
        bf16x8 af[4], bfr[4];
#pragma unroll
        for (int f = 0; f < 4; ++f) {
            af[f]  = *reinterpret_cast<const bf16x8*>(As + (wm * 64 + f * 16 + lr) * 32 + lg * 8);
            bfr[f] = *reinterpret_cast<const bf16x8*>(Bs + (wn * 64 + f * 16 + lr) * 32 + lg * 8);
        }
#pragma unroll
        for (int i = 0; i < 4; ++i)
#pragma unroll
            for (int j = 0; j < 4; ++j)
                acc[i][j] = __builtin_amdgcn_mfma_f32_16x16x32_bf16(af[i], bfr[j], acc[i][j], 0, 0, 0);
    }

#pragma unroll
    for (int i = 0; i < 4; ++i) {
#pragma unroll
        for (int j = 0; j < 4; ++j) {
            int col = n0 + wn * 64 + j * 16 + lr;
            if (NEDGE && col >= N) continue;
            float bv = (BIAS && kbeg == 0) ? bias[col] : 0.0f;
#pragma unroll
            for (int r = 0; r < 4; ++r) {
                int row = m0 + wm * 64 + i * 16 + lg * 4 + r;
                float v = acc[i][j][r] + bv;
                if (ACT == 1) v = 0.5f * v * (1.0f + erff(v * 0.70710678118654752f));
                if (ATOMIC) {
                    atomicAdd(reinterpret_cast<float*>(Cout) + (size_t)row * ldc + col, v);
                } else if (OUTBF16) {
                    reinterpret_cast<unsigned short*>(Cout)[(size_t)row * ldc + col] = f2bf(v);
                } else {
                    reinterpret_cast<float*>(Cout)[(size_t)row * ldc + col] = v;
                }
            }
        }
    }
}

// ---------------- head GEMM: 256x256 tile, BK=64, 8 waves, 4-slot LDS ring,
// counted-vmcnt pipeline (T3/T4), XOR swizzle (T2), setprio (T5), XCD swizzle (T1).
// C[2048][N] f32 = A[2048][K]bf16 @ Bt[N][K]^T, N-edge clamped.
__global__ __launch_bounds__(512, 2) void head_gemm_kernel(
    const unsigned short* __restrict__ A, const unsigned short* __restrict__ Bt,
    float* __restrict__ C, int N, int K) {
    // 4 half-slots x (A[256x32] + B[256x32]) bf16 = 4 x 32 KB = 128 KB
    __shared__ unsigned short lds[4][2][8192];
    const int tid = threadIdx.x;
    const int lane = tid & 63, wid = tid >> 6;
    const int wm = wid >> 2, wn = wid & 3;     // 2 x 4 wave grid
    const int lr = lane & 15, lg = lane >> 4;

    // bijective XCD swizzle (nwg % 8 == 0), M-fast logical order
    const int qx = gridDim.x >> 3;
    const int orig = blockIdx.x;
    const int wg = (orig & 7) * qx + (orig >> 3);
    const int m0 = (wg & 7) * 256;             // M = 2048 -> 8 M-tiles
    const int n0 = (wg >> 3) * 256;

    // staging chunk descriptors: physical chunk o (16B) in a slot-half holds
    // logical (r, kb) with kb swizzled: li = (s*16) ^ ((pr&7)<<4)
    const int o0 = tid, o1 = tid + 512;
    int rA0, kb0, rA1, kb1;
    { int pr = o0 >> 3, s = o0 & 7; int li = (s << 4) ^ ((pr & 7) << 4);
      rA0 = (pr << 1) | (li >> 6); kb0 = li & 63; }
    { int pr = o1 >> 3, s = o1 & 7; int li = (s << 4) ^ ((pr & 7) << 4);
      rA1 = (pr << 1) | (li >> 6); kb1 = li & 63; }
    const char* pA0 = (const char*)A + (size_t)(m0 + rA0) * (2 * K) + kb0;
    const char* pA1 = (const char*)A + (size_t)(m0 + rA1) * (2 * K) + kb1;
    const char* pB0 = (const char*)Bt + (size_t)min(n0 + rA0, N - 1) * (2 * K) + kb0;
    const char* pB1 = (const char*)Bt + (size_t)min(n0 + rA1, N - 1) * (2 * K) + kb1;
    const int dw0 = wid * 512;                 // wave-uniform LDS dest (shorts)
    const int dw1 = 4096 + wid * 512;

    // swizzled frag-read base: row pair-packed [128][128B], col-XOR by row bits
    const int swz = (((lr & 1) << 6) | (lg << 4)) ^ (((lr >> 1) & 7) << 4);
    const int pbA = (wm * 64 + (lr >> 1)) * 128 + swz;   // bytes within A part
    const int pbB = (wn * 32 + (lr >> 1)) * 128 + swz;   // bytes within B part

    auto stage = [&](int slot, int koff) {
        unsigned short* la = &lds[slot][0][0];
        unsigned short* lb = &lds[slot][1][0];
        gload16((const unsigned short*)(pA0 + koff), la + dw0);
        gload16((const unsigned short*)(pA1 + koff), la + dw1);
        gload16((const unsigned short*)(pB0 + koff), lb + dw0);
        gload16((const unsigned short*)(pB1 + koff), lb + dw1);
    };
    auto rdA = [&](int slot, int mf) -> bf16x8 {
        return *reinterpret_cast<const bf16x8*>(
            (const char*)lds + slot * 32768 + pbA + mf * 1024);
    };
    auto rdB = [&](int slot, int nf) -> bf16x8 {
        return *reinterpret_cast<const bf16x8*>(
            (const char*)lds + slot * 32768 + 16384 + pbB + nf * 1024);
    };

    const f32x4 zero4 = {0.0f, 0.0f, 0.0f, 0.0f};
    f32x4 acc[8][4];
#pragma unroll
    for (int i = 0; i < 8; ++i)
#pragma unroll
        for (int j = 0; j < 4; ++j) acc[i][j] = zero4;

#define MFMA_ROW(AF, MI) \
    acc[MI][0] = __builtin_amdgcn_mfma_f32_16x16x32_bf16(AF, bf0, acc[MI][0], 0, 0, 0); \
    acc[MI][1] = __builtin_amdgcn_mfma_f32_16x16x32_bf16(AF, bf1, acc[MI][1], 0, 0, 0); \
    acc[MI][2] = __builtin_amdgcn_mfma_f32_16x16x32_bf16(AF, bf2, acc[MI][2], 0, 0, 0); \
    acc[MI][3] = __builtin_amdgcn_mfma_f32_16x16x32_bf16(AF, bf3, acc[MI][3], 0, 0, 0);

    stage(0, 0);      // half 0 (tile 0, ks0) -> slot 0
    stage(1, 64);     // half 1 (tile 0, ks1) -> slot 1
    const int nk = K >> 6;
    for (int t = 0; t < nk; ++t) {
        const int cur = (t & 1) << 1;          // slot of this tile's ks0
        const int koff = t << 7;
        const bool pf = (t + 1 < nk);
        // ---- phase 1: ks0, mf 0-3 (wait half 2t; issue half 2t+2)
        vwait<4>();
        barrier_mem();
        if (pf) stage(cur ^ 2, koff + 128);
        bf16x8 bf0 = rdB(cur, 0), bf1 = rdB(cur, 1), bf2 = rdB(cur, 2), bf3 = rdB(cur, 3);
        bf16x8 a0 = rdA(cur, 0), a1 = rdA(cur, 1), a2 = rdA(cur, 2), a3 = rdA(cur, 3);
        __builtin_amdgcn_s_setprio(1);
        MFMA_ROW(a0, 0) MFMA_ROW(a1, 1) MFMA_ROW(a2, 2) MFMA_ROW(a3, 3)
        __builtin_amdgcn_s_setprio(0);
        // ---- phase 2: ks0, mf 4-7 (issue half 2t+3; reuse B frags)
        if (pf) stage((cur ^ 2) | 1, koff + 192);
        a0 = rdA(cur, 4); a1 = rdA(cur, 5); a2 = rdA(cur, 6); a3 = rdA(cur, 7);
        __builtin_amdgcn_s_setprio(1);
        MFMA_ROW(a0, 4) MFMA_ROW(a1, 5) MFMA_ROW(a2, 6) MFMA_ROW(a3, 7)
        __builtin_amdgcn_s_setprio(0);
        // ---- phase 3: ks1, mf 0-3 (wait half 2t+1; counted, never 0 mid-loop)
        if (pf) vwait<8>(); else vwait<0>();
        barrier_mem();
        const int nxt = cur | 1;
        bf0 = rdB(nxt, 0); bf1 = rdB(nxt, 1); bf2 = rdB(nxt, 2); bf3 = rdB(nxt, 3);
        a0 = rdA(nxt, 0); a1 = rdA(nxt, 1); a2 = rdA(nxt, 2); a3 = rdA(nxt, 3);
        __builtin_amdgcn_s_setprio(1);
        MFMA_ROW(a0, 0) MFMA_ROW(a1, 1) MFMA_ROW(a2, 2) MFMA_ROW(a3, 3)
        __builtin_amdgcn_s_setprio(0);
        // ---- phase 4: ks1, mf 4-7
        a0 = rdA(nxt, 4); a1 = rdA(nxt, 5); a2 = rdA(nxt, 6); a3 = rdA(nxt, 7);
        __builtin_amdgcn_s_setprio(1);
        MFMA_ROW(a0, 4) MFMA_ROW(a1, 5) MFMA_ROW(a2, 6) MFMA_ROW(a3, 7)
        __builtin_amdgcn_s_setprio(0);
    }
#undef MFMA_ROW

#pragma unroll
    for (int mf = 0; mf < 8; ++mf)
#pragma unroll
        for (int nf = 0; nf < 4; ++nf) {
            int col = n0 + wn * 64 + nf * 16 + lr;
            if (col < N) {
#pragma unroll
                for (int r = 0; r < 4; ++r) {
                    int row = m0 + wm * 128 + mf * 16 + lg * 4 + r;
                    C[(size_t)row * N + col] = acc[mf][nf][r];
                }
            }
        }
}

// ---------------- V transpose: qkv v-part [t][d] -> vt[b][h][d][t] (bf16)
__global__ __launch_bounds__(256) void vtrans_kernel(
    const unsigned short* __restrict__ qkv, unsigned short* __restrict__ vt) {
    __shared__ unsigned short tile[32][33];
    int bh = blockIdx.z; int b = bh >> 4, h = bh & 15;
    int t0 = blockIdx.x * 32, d0 = blockIdx.y * 32;
    int tx = threadIdx.x, ty = threadIdx.y;  // (32,8)
#pragma unroll
    for (int i = 0; i < 4; ++i)
        tile[ty + i * 8][tx] =
            qkv[(size_t)(b * NT + t0 + ty + i * 8) * 3072 + 2048 + h * 64 + d0 + tx];
    __syncthreads();
#pragma unroll
    for (int i = 0; i < 4; ++i)
        vt[((size_t)(b * NH + h) * 64 + d0 + ty + i * 8) * NT + t0 + tx] = tile[tx][ty + i * 8];
}

// ---------------- causal flash attention: 1 wave per (b, h, 32 q-rows)
__global__ __launch_bounds__(64) void attn_kernel(
    const unsigned short* __restrict__ qkv, const unsigned short* __restrict__ vt,
    unsigned short* __restrict__ o) {
    __shared__ unsigned short Vs[64][72];
    __shared__ unsigned short Ps[32][72];
    const int qt = blockIdx.x;   // 0..31
    const int h  = blockIdx.y;   // 0..15
    const int b  = blockIdx.z;   // 0..1
    const int lane = threadIdx.x;
    const int lr = lane & 15, lg = lane >> 4;

    const unsigned short* qbase = qkv + (size_t)(b * NT + qt * 32) * 3072 + h * 64;
    bf16x8 qf[2][2];
#pragma unroll
    for (int mf = 0; mf < 2; ++mf)
#pragma unroll
        for (int kc = 0; kc < 2; ++kc)
            qf[mf][kc] = *reinterpret_cast<const bf16x8*>(
                qbase + (size_t)(mf * 16 + lr) * 3072 + kc * 32 + lg * 8);

    const f32x4 zero4 = {0.0f, 0.0f, 0.0f, 0.0f};
    f32x4 oacc[2][4];
    float mrow[2][4], lsum[2][4];
#pragma unroll
    for (int mf = 0; mf < 2; ++mf) {
#pragma unroll
        for (int nf = 0; nf < 4; ++nf) oacc[mf][nf] = zero4;
#pragma unroll
        for (int r = 0; r < 4; ++r) { mrow[mf][r] = -INFINITY; lsum[mf][r] = 0.0f; }
    }

    const int qend = qt * 32 + 32;
    const int nkt = (qend + 63) >> 6;
    const unsigned short* kbase = qkv + (size_t)(b * NT) * 3072 + NC + h * 64;
    const unsigned short* vbase = vt + (size_t)((b * NH + h) * 64) * NT;

    for (int kt = 0; kt < nkt; ++kt) {
        __syncthreads();
#pragma unroll
        for (int i = 0; i < 8; ++i) {
            int chunk = lane + i * 64;
            int d = chunk >> 3;
            int kk = (chunk & 7) * 8;
            *reinterpret_cast<bf16x8*>(&Vs[d][kk]) =
                *reinterpret_cast<const bf16x8*>(vbase + (size_t)d * NT + kt * 64 + kk);
        }
        f32x4 s[2][4];
#pragma unroll
        for (int mf = 0; mf < 2; ++mf)
#pragma unroll
            for (int jf = 0; jf < 4; ++jf) s[mf][jf] = zero4;
#pragma unroll
        for (int kc = 0; kc < 2; ++kc) {
            bf16x8 kf[4];
#pragma unroll
            for (int jf = 0; jf < 4; ++jf)
                kf[jf] = *reinterpret_cast<const bf16x8*>(
                    kbase + (size_t)(kt * 64 + jf * 16 + lr) * 3072 + kc * 32 + lg * 8);
#pragma unroll
            for (int mf = 0; mf < 2; ++mf)
#pragma unroll
                for (int jf = 0; jf < 4; ++jf)
                    s[mf][jf] = __builtin_amdgcn_mfma_f32_16x16x32_bf16(
                        qf[mf][kc], kf[jf], s[mf][jf], 0, 0, 0);
        }
        const bool lastt = (kt == nkt - 1);
#pragma unroll
        for (int mf = 0; mf < 2; ++mf) {
#pragma unroll
            for (int r = 0; r < 4; ++r) {
                int rowg = qt * 32 + mf * 16 + lg * 4 + r;
                float tmax = -INFINITY;
#pragma unroll
                for (int jf = 0; jf < 4; ++jf) {
                    float v = s[mf][jf][r] * 0.125f;
                    if (lastt) {
                        int colg = kt * 64 + jf * 16 + lr;
                        if (colg > rowg) v = -INFINITY;
                    }
                    s[mf][jf][r] = v;
                    tmax = fmaxf(tmax, v);
                }
                tmax = fmaxf(tmax, __shfl_xor(tmax, 1, 64));
                tmax = fmaxf(tmax, __shfl_xor(tmax, 2, 64));
                tmax = fmaxf(tmax, __shfl_xor(tmax, 4, 64));
                tmax = fmaxf(tmax, __shfl_xor(tmax, 8, 64));
                float mnew = fmaxf(mrow[mf][r], tmax);
                float corr = __expf(mrow[mf][r] - mnew);
                float ps = 0.0f;
#pragma unroll
                for (int jf = 0; jf < 4; ++jf) {
                    float p = __expf(s[mf][jf][r] - mnew);
                    s[mf][jf][r] = p;
                    ps += p;
                }
                ps += __shfl_xor(ps, 1, 64);
                ps += __shfl_xor(ps, 2, 64);
                ps += __shfl_xor(ps, 4, 64);
                ps += __shfl_xor(ps, 8, 64);
                lsum[mf][r] = lsum[mf][r] * corr + ps;
                mrow[mf][r] = mnew;
#pragma unroll
                for (int nf = 0; nf < 4; ++nf) oacc[mf][nf][r] *= corr;
            }
        }
#pragma unroll
        for (int mf = 0; mf < 2; ++mf)
#pragma unroll
            for (int jf = 0; jf < 4; ++jf)
#pragma unroll
                for (int r = 0; r < 4; ++r)
                    Ps[mf * 16 + lg * 4 + r][jf * 16 + lr] = f2bf(s[mf][jf][r]);
        __syncthreads();
#pragma unroll
        for (int kc = 0; kc < 2; ++kc) {
            bf16x8 pf[2], vf[4];
#pragma unroll
            for (int mf = 0; mf < 2; ++mf)
                pf[mf] = *reinterpret_cast<const bf16x8*>(&Ps[mf * 16 + lr][kc * 32 + lg * 8]);
#pragma unroll
            for (int nf = 0; nf < 4; ++nf)
                vf[nf] = *reinterpret_cast<const bf16x8*>(&Vs[nf * 16 + lr][kc * 32 + lg * 8]);
#pragma unroll
            for (int mf = 0; mf < 2; ++mf)
#pragma unroll
                for (int nf = 0; nf < 4; ++nf)
                    oacc[mf][nf] = __builtin_amdgcn_mfma_f32_16x16x32_bf16(
                        pf[mf], vf[nf], oacc[mf][nf], 0, 0, 0);
        }
    }

    unsigned short* ob = o + (size_t)(b * NT + qt * 32) * NC + h * 64;
#pragma unroll
    for (int mf = 0; mf < 2; ++mf)
#pragma unroll
        for (int nf = 0; nf < 4; ++nf)
#pragma unroll
            for (int r = 0; r < 4; ++r) {
                float v = oacc[mf][nf][r] / lsum[mf][r];
                ob[(size_t)(mf * 16 + lg * 4 + r) * NC + nf * 16 + lr] = f2bf(v);
            }
}

extern "C" void kernel_launch(void* const* d_in, const int* in_sizes, int n_in,
                              void* d_out, int out_size, void* d_ws, size_t ws_size,
                              hipStream_t stream) {
    (void)in_sizes; (void)n_in; (void)out_size; (void)ws_size;
    const int*   idx    = (const int*)  d_in[0];
    const float* tok    = (const float*)d_in[1];
    const float* pos    = (const float*)d_in[2];
    const float* qkv_w  = (const float*)d_in[3];
    const float* qkv_b  = (const float*)d_in[4];
    const float* out_w  = (const float*)d_in[5];
    const float* out_b  = (const float*)d_in[6];
    const float* ln1_s  = (const float*)d_in[7];
    const float* ln1_b  = (const float*)d_in[8];
    const float* ln2_s  = (const float*)d_in[9];
    const float* ln2_b  = (const float*)d_in[10];
    const float* ffn_w1 = (const float*)d_in[11];
    const float* ffn_b1 = (const float*)d_in[12];
    const float* ffn_w2 = (const float*)d_in[13];
    const float* ffn_b2 = (const float*)d_in[14];
    const float* lnf_s  = (const float*)d_in[15];
    const float* lnf_b  = (const float*)d_in[16];

    char* p = (char*)d_ws;
    float* x              = (float*)p;          p += (size_t)NM * NC * 4;
    unsigned short* hbuf  = (unsigned short*)p; p += (size_t)NM * NC * 2;
    unsigned short* qkvb  = (unsigned short*)p; p += (size_t)NM * 3 * NC * 2;
    unsigned short* obuf  = (unsigned short*)p; p += (size_t)NM * NC * 2;
    unsigned short* gbuf  = (unsigned short*)p; p += (size_t)NM * NFF * 2;
    unsigned short* vtb   = (unsigned short*)p; p += (size_t)NB * NH * 64 * NT * 2;
    unsigned short* wq    = (unsigned short*)p; p += (size_t)3 * NC * NC * 2;
    unsigned short* wo    = (unsigned short*)p; p += (size_t)NC * NC * 2;
    unsigned short* w1    = (unsigned short*)p; p += (size_t)NC * NFF * 2;
    unsigned short* w2    = (unsigned short*)p; p += (size_t)NFF * NC * 2;
    unsigned short* temb  = (unsigned short*)p; p += (size_t)NV * NC * 2;

    {
        size_t n4 = (size_t)NV * NC / 4;
        int blocks = (int)((n4 + 255) / 256);
        cvt_bf16_kernel<<<blocks, 256, 0, stream>>>(tok, temb, n4);
    }
    embed_kernel<<<NM, 256, 0, stream>>>(idx, tok, pos, x);

    for (int l = 0; l < NL; ++l) {
        wtrans_kernel<<<dim3(96, 32),  dim3(32, 8), 0, stream>>>(qkv_w + (size_t)l * NC * 3 * NC, wq, NC, 3 * NC);
        wtrans_kernel<<<dim3(32, 32),  dim3(32, 8), 0, stream>>>(out_w + (size_t)l * NC * NC, wo, NC, NC);
        wtrans_kernel<<<dim3(128, 32), dim3(32, 8), 0, stream>>>(ffn_w1 + (size_t)l * NC * NFF, w1, NC, NFF);
        wtrans_kernel<<<dim3(32, 128), dim3(32, 8), 0, stream>>>(ffn_w2 + (size_t)l * NFF * NC, w2, NFF, NC);

        ln_kernel<<<NM, 256, 0, stream>>>(x, ln1_s + (size_t)l * NC, ln1_b + (size_t)l * NC, hbuf);
        gemm_kernel<0, true, true, false, false><<<dim3(16, 24), 256, 0, stream>>>(
            hbuf, wq, qkv_b + (size_t)l * 3 * NC, qkvb, 3 * NC, NC, 3 * NC, NC);
        vtrans_kernel<<<dim3(32, 2, 32), dim3(32, 8), 0, stream>>>(qkvb, vtb);
        attn_kernel<<<dim3(32, 16, 2), 64, 0, stream>>>(qkvb, vtb, obuf);
        gemm_kernel<0, true, false, false, true><<<dim3(16, 8, 2), 256, 0, stream>>>(
            obuf, wo, out_b + (size_t)l * NC, x, NC, NC, NC, NC / 2);
        ln_kernel<<<NM, 256, 0, stream>>>(x, ln2_s + (size_t)l * NC, ln2_b + (size_t)l * NC, hbuf);
        gemm_kernel<1, true, true, false, false><<<dim3(16, 32), 256, 0, stream>>>(
            hbuf, w1, ffn_b1 + (size_t)l * NFF, gbuf, NFF, NC, NFF, NC);
        gemm_kernel<0, true, false, false, true><<<dim3(16, 8, 4), 256, 0, stream>>>(
            gbuf, w2, ffn_b2 + (size_t)l * NC, x, NC, NFF, NC, NFF / 4);
    }
    ln_kernel<<<NM, 256, 0, stream>>>(x, lnf_s, lnf_b, hbuf);
    // tied head: 256x256 deep-pipelined, grid = 8 M-tiles x 197 N-tiles
    head_gemm_kernel<<<dim3(8 * 197), 512, 0, stream>>>(hbuf, temb, (float*)d_out, NV, NC);
}

// Round 4
// 2011.562 us; speedup vs baseline: 1.2700x; 1.1038x over previous
//
#include <hip/hip_runtime.h>
#include <hip/hip_bf16.h>

#define NL 8
#define NV 50257
#define NC 1024
#define NH 16
#define NT 1024
#define NFF 4096
#define NB 2
#define NM (NB*NT)   // 2048 rows

typedef __attribute__((ext_vector_type(8))) short bf16x8;
typedef __attribute__((ext_vector_type(4))) float f32x4;

__device__ __forceinline__ unsigned short f2bf(float f) {
    union { float f; unsigned u; } a; a.f = f;
    unsigned r = a.u + 0x7FFFu + ((a.u >> 16) & 1u);
    return (unsigned short)(r >> 16);
}

__device__ __forceinline__ void gload16(const unsigned short* g, unsigned short* l) {
    __builtin_amdgcn_global_load_lds(
        (const __attribute__((address_space(1))) unsigned int*)g,
        (__attribute__((address_space(3))) unsigned int*)l,
        16, 0, 0);
}

template<int VN> __device__ __forceinline__ void vwait() {
    asm volatile("s_waitcnt vmcnt(%0)" :: "n"(VN) : "memory");
}
__device__ __forceinline__ void barrier_mem() {
    asm volatile("" ::: "memory");
    __builtin_amdgcn_s_barrier();
    asm volatile("" ::: "memory");
}

// ---------------- embedding: x[b,t,:] = tok_emb[idx[b,t],:] + pos_emb[t,:]
__global__ __launch_bounds__(256) void embed_kernel(
    const int* __restrict__ idx, const float* __restrict__ te,
    const float* __restrict__ pe, float* __restrict__ x) {
    int row = blockIdx.x;            // 0..2047 = b*1024 + t
    int t = row & (NT - 1);
    int id = idx[row];
    const float4 a = reinterpret_cast<const float4*>(te + (size_t)id * NC)[threadIdx.x];
    const float4 b = reinterpret_cast<const float4*>(pe + (size_t)t * NC)[threadIdx.x];
    float4 o; o.x = a.x + b.x; o.y = a.y + b.y; o.z = a.z + b.z; o.w = a.w + b.w;
    reinterpret_cast<float4*>(x + (size_t)row * NC)[threadIdx.x] = o;
}

// ---------------- f32 -> bf16 bulk convert (tok_emb)
__global__ __launch_bounds__(256) void cvt_bf16_kernel(
    const float* __restrict__ in, unsigned short* __restrict__ out, size_t n4) {
    size_t i = (size_t)blockIdx.x * 256 + threadIdx.x;
    if (i >= n4) return;
    float4 v = reinterpret_cast<const float4*>(in)[i];
    uint2 u;
    u.x = (unsigned)f2bf(v.x) | ((unsigned)f2bf(v.y) << 16);
    u.y = (unsigned)f2bf(v.z) | ((unsigned)f2bf(v.w) << 16);
    reinterpret_cast<uint2*>(out)[i] = u;
}

// ---------------- fused weight transpose+convert for one layer (4 matrices)
// W[K][N] f32 -> Wt[N][K] bf16, segments: qkv_w, out_w, ffn_w1, ffn_w2
__global__ __launch_bounds__(256) void wtrans4_kernel(
    const float* __restrict__ s0, const float* __restrict__ s1,
    const float* __restrict__ s2, const float* __restrict__ s3,
    unsigned short* __restrict__ d0, unsigned short* __restrict__ d1,
    unsigned short* __restrict__ d2, unsigned short* __restrict__ d3) {
    __shared__ float tile[32][33];
    int bid = blockIdx.x;
    const float* W; unsigned short* D; int K, N, tn, tk;
    if (bid < 3072)      { W = s0; D = d0; K = 1024; N = 3072; tn = bid % 96;  tk = bid / 96; }
    else if (bid < 4096) { int t = bid - 3072; W = s1; D = d1; K = 1024; N = 1024; tn = t & 31;  tk = t >> 5; }
    else if (bid < 8192) { int t = bid - 4096; W = s2; D = d2; K = 1024; N = 4096; tn = t & 127; tk = t >> 7; }
    else                 { int t = bid - 8192; W = s3; D = d3; K = 4096; N = 1024; tn = t & 31;  tk = t >> 5; }
    int n0 = tn * 32, k0 = tk * 32;
    int tx = threadIdx.x, ty = threadIdx.y;  // (32,8)
#pragma unroll
    for (int i = 0; i < 4; ++i)
        tile[ty + i * 8][tx] = W[(size_t)(k0 + ty + i * 8) * N + n0 + tx];
    __syncthreads();
#pragma unroll
    for (int i = 0; i < 4; ++i)
        D[(size_t)(n0 + ty + i * 8) * K + k0 + tx] = f2bf(tile[tx][ty + i * 8]);
}

// ---------------- layernorm (f32 in -> bf16 out), one block per row, C=1024
__global__ __launch_bounds__(256) void ln_kernel(
    const float* __restrict__ x, const float* __restrict__ gam,
    const float* __restrict__ bet, unsigned short* __restrict__ out) {
    __shared__ float red[4];
    int row = blockIdx.x, tid = threadIdx.x;
    const float4 v = reinterpret_cast<const float4*>(x + (size_t)row * NC)[tid];
    float s = v.x + v.y + v.z + v.w;
#pragma unroll
    for (int m = 32; m >= 1; m >>= 1) s += __shfl_xor(s, m, 64);
    if ((tid & 63) == 0) red[tid >> 6] = s;
    __syncthreads();
    float mean = (red[0] + red[1] + red[2] + red[3]) * (1.0f / NC);
    __syncthreads();
    float dx = v.x - mean, dy = v.y - mean, dz = v.z - mean, dw = v.w - mean;
    float q = dx * dx + dy * dy + dz * dz + dw * dw;
#pragma unroll
    for (int m = 32; m >= 1; m >>= 1) q += __shfl_xor(q, m, 64);
    if ((tid & 63) == 0) red[tid >> 6] = q;
    __syncthreads();
    float var = (red[0] + red[1] + red[2] + red[3]) * (1.0f / NC);
    float rstd = rsqrtf(var + 1e-5f);
    int c = tid * 4;
    const float4 g4 = reinterpret_cast<const float4*>(gam)[tid];
    const float4 b4 = reinterpret_cast<const float4*>(bet)[tid];
    uint2 u;
    u.x = (unsigned)f2bf(dx * rstd * g4.x + b4.x) |
          ((unsigned)f2bf(dy * rstd * g4.y + b4.y) << 16);
    u.y = (unsigned)f2bf(dz * rstd * g4.z + b4.z) |
          ((unsigned)f2bf(dw * rstd * g4.w + b4.w) << 16);
    reinterpret_cast<uint2*>(out + (size_t)row * NC + c)[0] = u;
}

// ---------------- GEMM: C[M][N] = A[M][K](bf16) * Bt[N][K](bf16)^T
// 128x128 tile, BK=32, glds staging, DOUBLE-BUFFERED with 1-tile lookahead
// (T3-minimum: stage(t+1) issued BEFORE compute(t); single barrier per tile,
//  so the barrier's vmcnt(0) drain waits on loads issued a full phase earlier).
template<int ACT, bool BIAS, bool OUTBF16, bool ATOMIC>
__global__ __launch_bounds__(256) void gemm_kernel(
    const unsigned short* __restrict__ A, const unsigned short* __restrict__ Bt,
    const float* __restrict__ bias, void* __restrict__ Cout,
    int N, int K, int ldc, int ksub) {
    __shared__ unsigned short As[2][128 * 32];
    __shared__ unsigned short Bs[2][128 * 32];
    const int tid = threadIdx.x;
    const int lane = tid & 63;
    const int wave = tid >> 6;
    const int wm = wave >> 1, wn = wave & 1;
    const int lr = lane & 15, lg = lane >> 4;
    const int m0 = blockIdx.x * 128, n0 = blockIdx.y * 128;
    const int kbeg = blockIdx.z * ksub, kend = kbeg + ksub;

    const int r0 = tid >> 2;            // staging row within 64-row half
    const int c0 = (tid & 3) * 8;       // staging col (elements)
    const unsigned short* Ag0 = A + (size_t)(m0 + r0) * K + c0;
    const unsigned short* Ag1 = A + (size_t)(m0 + r0 + 64) * K + c0;
    const unsigned short* Bg0 = Bt + (size_t)(n0 + r0) * K + c0;
    const unsigned short* Bg1 = Bt + (size_t)(n0 + r0 + 64) * K + c0;
    const int dw0 = wave * 512;         // wave-uniform LDS dest (shorts)
    const int dw1 = 2048 + wave * 512;

    const f32x4 zero4 = {0.0f, 0.0f, 0.0f, 0.0f};
    f32x4 acc[4][4];
#pragma unroll
    for (int i = 0; i < 4; ++i)
#pragma unroll
        for (int j = 0; j < 4; ++j) acc[i][j] = zero4;

    auto stage = [&](int buf, int k0) {
        gload16(Ag0 + k0, &As[buf][dw0]);
        gload16(Ag1 + k0, &As[buf][dw1]);
        gload16(Bg0 + k0, &Bs[buf][dw0]);
        gload16(Bg1 + k0, &Bs[buf][dw1]);
    };

    stage(0, kbeg);
    __syncthreads();                    // drains prologue loads
    int cur = 0;
    for (int k0 = kbeg; k0 < kend; k0 += 32) {
        if (k0 + 32 < kend) stage(cur ^ 1, k0 + 32);   // prefetch next tile
        bf16x8 af[4], bfr[4];
#pragma unroll
        for (int f = 0; f < 4; ++f) {
            af[f]  = *reinterpret_cast<const bf16x8*>(&As[cur][(wm * 64 + f * 16 + lr) * 32 + lg * 8]);
            bfr[f] = *reinterpret_cast<const bf16x8*>(&Bs[cur][(wn * 64 + f * 16 + lr) * 32 + lg * 8]);
        }
#pragma unroll
        for (int i = 0; i < 4; ++i)
#pragma unroll
            for (int j = 0; j < 4; ++j)
                acc[i][j] = __builtin_amdgcn_mfma_f32_16x16x32_bf16(af[i], bfr[j], acc[i][j], 0, 0, 0);
        __syncthreads();                // drains prefetch (issued pre-compute)
        cur ^= 1;
    }

#pragma unroll
    for (int i = 0; i < 4; ++i) {
#pragma unroll
        for (int j = 0; j < 4; ++j) {
            int col = n0 + wn * 64 + j * 16 + lr;
            float bv = (BIAS && kbeg == 0) ? bias[col] : 0.0f;
#pragma unroll
            for (int r = 0; r < 4; ++r) {
                int row = m0 + wm * 64 + i * 16 + lg * 4 + r;
                float v = acc[i][j][r] + bv;
                if (ACT == 1) v = 0.5f * v * (1.0f + erff(v * 0.70710678118654752f));
                if (ATOMIC) {
                    atomicAdd(reinterpret_cast<float*>(Cout) + (size_t)row * ldc + col, v);
                } else if (OUTBF16) {
                    reinterpret_cast<unsigned short*>(Cout)[(size_t)row * ldc + col] = f2bf(v);
                } else {
                    reinterpret_cast<float*>(Cout)[(size_t)row * ldc + col] = v;
                }
            }
        }
    }
}

// ---------------- head GEMM: 256x256 tile, BK=64, 8 waves, 4-slot LDS ring,
// counted-vmcnt pipeline (T3/T4), XOR swizzle (T2), setprio (T5), XCD swizzle (T1).
__global__ __launch_bounds__(512, 2) void head_gemm_kernel(
    const unsigned short* __restrict__ A, const unsigned short* __restrict__ Bt,
    float* __restrict__ C, int N, int K) {
    __shared__ unsigned short lds[4][2][8192];
    const int tid = threadIdx.x;
    const int lane = tid & 63, wid = tid >> 6;
    const int wm = wid >> 2, wn = wid & 3;     // 2 x 4 wave grid
    const int lr = lane & 15, lg = lane >> 4;

    const int qx = gridDim.x >> 3;
    const int orig = blockIdx.x;
    const int wg = (orig & 7) * qx + (orig >> 3);
    const int m0 = (wg & 7) * 256;
    const int n0 = (wg >> 3) * 256;

    const int o0 = tid, o1 = tid + 512;
    int rA0, kb0, rA1, kb1;
    { int pr = o0 >> 3, s = o0 & 7; int li = (s << 4) ^ ((pr & 7) << 4);
      rA0 = (pr << 1) | (li >> 6); kb0 = li & 63; }
    { int pr = o1 >> 3, s = o1 & 7; int li = (s << 4) ^ ((pr & 7) << 4);
      rA1 = (pr << 1) | (li >> 6); kb1 = li & 63; }
    const char* pA0 = (const char*)A + (size_t)(m0 + rA0) * (2 * K) + kb0;
    const char* pA1 = (const char*)A + (size_t)(m0 + rA1) * (2 * K) + kb1;
    const char* pB0 = (const char*)Bt + (size_t)min(n0 + rA0, N - 1) * (2 * K) + kb0;
    const char* pB1 = (const char*)Bt + (size_t)min(n0 + rA1, N - 1) * (2 * K) + kb1;
    const int dw0 = wid * 512;
    const int dw1 = 4096 + wid * 512;

    const int swz = (((lr & 1) << 6) | (lg << 4)) ^ (((lr >> 1) & 7) << 4);
    const int pbA = (wm * 64 + (lr >> 1)) * 128 + swz;
    const int pbB = (wn * 32 + (lr >> 1)) * 128 + swz;

    auto stage = [&](int slot, int koff) {
        unsigned short* la = &lds[slot][0][0];
        unsigned short* lb = &lds[slot][1][0];
        gload16((const unsigned short*)(pA0 + koff), la + dw0);
        gload16((const unsigned short*)(pA1 + koff), la + dw1);
        gload16((const unsigned short*)(pB0 + koff), lb + dw0);
        gload16((const unsigned short*)(pB1 + koff), lb + dw1);
    };
    auto rdA = [&](int slot, int mf) -> bf16x8 {
        return *reinterpret_cast<const bf16x8*>(
            (const char*)lds + slot * 32768 + pbA + mf * 1024);
    };
    auto rdB = [&](int slot, int nf) -> bf16x8 {
        return *reinterpret_cast<const bf16x8*>(
            (const char*)lds + slot * 32768 + 16384 + pbB + nf * 1024);
    };

    const f32x4 zero4 = {0.0f, 0.0f, 0.0f, 0.0f};
    f32x4 acc[8][4];
#pragma unroll
    for (int i = 0; i < 8; ++i)
#pragma unroll
        for (int j = 0; j < 4; ++j) acc[i][j] = zero4;

#define MFMA_ROW(AF, MI) \
    acc[MI][0] = __builtin_amdgcn_mfma_f32_16x16x32_bf16(AF, bf0, acc[MI][0], 0, 0, 0); \
    acc[MI][1] = __builtin_amdgcn_mfma_f32_16x16x32_bf16(AF, bf1, acc[MI][1], 0, 0, 0); \
    acc[MI][2] = __builtin_amdgcn_mfma_f32_16x16x32_bf16(AF, bf2, acc[MI][2], 0, 0, 0); \
    acc[MI][3] = __builtin_amdgcn_mfma_f32_16x16x32_bf16(AF, bf3, acc[MI][3], 0, 0, 0);

    stage(0, 0);
    stage(1, 64);
    const int nk = K >> 6;
    for (int t = 0; t < nk; ++t) {
        const int cur = (t & 1) << 1;
        const int koff = t << 7;
        const bool pf = (t + 1 < nk);
        vwait<4>();
        barrier_mem();
        if (pf) stage(cur ^ 2, koff + 128);
        bf16x8 bf0 = rdB(cur, 0), bf1 = rdB(cur, 1), bf2 = rdB(cur, 2), bf3 = rdB(cur, 3);
        bf16x8 a0 = rdA(cur, 0), a1 = rdA(cur, 1), a2 = rdA(cur, 2), a3 = rdA(cur, 3);
        __builtin_amdgcn_s_setprio(1);
        MFMA_ROW(a0, 0) MFMA_ROW(a1, 1) MFMA_ROW(a2, 2) MFMA_ROW(a3, 3)
        __builtin_amdgcn_s_setprio(0);
        if (pf) stage((cur ^ 2) | 1, koff + 192);
        a0 = rdA(cur, 4); a1 = rdA(cur, 5); a2 = rdA(cur, 6); a3 = rdA(cur, 7);
        __builtin_amdgcn_s_setprio(1);
        MFMA_ROW(a0, 4) MFMA_ROW(a1, 5) MFMA_ROW(a2, 6) MFMA_ROW(a3, 7)
        __builtin_amdgcn_s_setprio(0);
        if (pf) vwait<8>(); else vwait<0>();
        barrier_mem();
        const int nxt = cur | 1;
        bf0 = rdB(nxt, 0); bf1 = rdB(nxt, 1); bf2 = rdB(nxt, 2); bf3 = rdB(nxt, 3);
        a0 = rdA(nxt, 0); a1 = rdA(nxt, 1); a2 = rdA(nxt, 2); a3 = rdA(nxt, 3);
        __builtin_amdgcn_s_setprio(1);
        MFMA_ROW(a0, 0) MFMA_ROW(a1, 1) MFMA_ROW(a2, 2) MFMA_ROW(a3, 3)
        __builtin_amdgcn_s_setprio(0);
        a0 = rdA(nxt, 4); a1 = rdA(nxt, 5); a2 = rdA(nxt, 6); a3 = rdA(nxt, 7);
        __builtin_amdgcn_s_setprio(1);
        MFMA_ROW(a0, 4) MFMA_ROW(a1, 5) MFMA_ROW(a2, 6) MFMA_ROW(a3, 7)
        __builtin_amdgcn_s_setprio(0);
    }
#undef MFMA_ROW

#pragma unroll
    for (int mf = 0; mf < 8; ++mf)
#pragma unroll
        for (int nf = 0; nf < 4; ++nf) {
            int col = n0 + wn * 64 + nf * 16 + lr;
            if (col < N) {
#pragma unroll
                for (int r = 0; r < 4; ++r) {
                    int row = m0 + wm * 128 + mf * 16 + lg * 4 + r;
                    C[(size_t)row * N + col] = acc[mf][nf][r];
                }
            }
        }
}

// ---------------- V transpose: qkv v-part [t][d] -> vt[b][h][d][t] (bf16)
__global__ __launch_bounds__(256) void vtrans_kernel(
    const unsigned short* __restrict__ qkv, unsigned short* __restrict__ vt) {
    __shared__ unsigned short tile[32][33];
    int bh = blockIdx.z; int b = bh >> 4, h = bh & 15;
    int t0 = blockIdx.x * 32, d0 = blockIdx.y * 32;
    int tx = threadIdx.x, ty = threadIdx.y;  // (32,8)
#pragma unroll
    for (int i = 0; i < 4; ++i)
        tile[ty + i * 8][tx] =
            qkv[(size_t)(b * NT + t0 + ty + i * 8) * 3072 + 2048 + h * 64 + d0 + tx];
    __syncthreads();
#pragma unroll
    for (int i = 0; i < 4; ++i)
        vt[((size_t)(b * NH + h) * 64 + d0 + ty + i * 8) * NT + t0 + tx] = tile[tx][ty + i * 8];
}

// ---------------- causal flash attention: 1 wave per (b, h, 32 q-rows)
__global__ __launch_bounds__(64) void attn_kernel(
    const unsigned short* __restrict__ qkv, const unsigned short* __restrict__ vt,
    unsigned short* __restrict__ o) {
    __shared__ unsigned short Vs[64][72];
    __shared__ unsigned short Ps[32][72];
    const int qt = blockIdx.x;   // 0..31
    const int h  = blockIdx.y;   // 0..15
    const int b  = blockIdx.z;   // 0..1
    const int lane = threadIdx.x;
    const int lr = lane & 15, lg = lane >> 4;

    const unsigned short* qbase = qkv + (size_t)(b * NT + qt * 32) * 3072 + h * 64;
    bf16x8 qf[2][2];
#pragma unroll
    for (int mf = 0; mf < 2; ++mf)
#pragma unroll
        for (int kc = 0; kc < 2; ++kc)
            qf[mf][kc] = *reinterpret_cast<const bf16x8*>(
                qbase + (size_t)(mf * 16 + lr) * 3072 + kc * 32 + lg * 8);

    const f32x4 zero4 = {0.0f, 0.0f, 0.0f, 0.0f};
    f32x4 oacc[2][4];
    float mrow[2][4], lsum[2][4];
#pragma unroll
    for (int mf = 0; mf < 2; ++mf) {
#pragma unroll
        for (int nf = 0; nf < 4; ++nf) oacc[mf][nf] = zero4;
#pragma unroll
        for (int r = 0; r < 4; ++r) { mrow[mf][r] = -INFINITY; lsum[mf][r] = 0.0f; }
    }

    const int qend = qt * 32 + 32;
    const int nkt = (qend + 63) >> 6;
    const unsigned short* kbase = qkv + (size_t)(b * NT) * 3072 + NC + h * 64;
    const unsigned short* vbase = vt + (size_t)((b * NH + h) * 64) * NT;

    for (int kt = 0; kt < nkt; ++kt) {
        __syncthreads();
#pragma unroll
        for (int i = 0; i < 8; ++i) {
            int chunk = lane + i * 64;
            int d = chunk >> 3;
            int kk = (chunk & 7) * 8;
            *reinterpret_cast<bf16x8*>(&Vs[d][kk]) =
                *reinterpret_cast<const bf16x8*>(vbase + (size_t)d * NT + kt * 64 + kk);
        }
        f32x4 s[2][4];
#pragma unroll
        for (int mf = 0; mf < 2; ++mf)
#pragma unroll
            for (int jf = 0; jf < 4; ++jf) s[mf][jf] = zero4;
#pragma unroll
        for (int kc = 0; kc < 2; ++kc) {
            bf16x8 kf[4];
#pragma unroll
            for (int jf = 0; jf < 4; ++jf)
                kf[jf] = *reinterpret_cast<const bf16x8*>(
                    kbase + (size_t)(kt * 64 + jf * 16 + lr) * 3072 + kc * 32 + lg * 8);
#pragma unroll
            for (int mf = 0; mf < 2; ++mf)
#pragma unroll
                for (int jf = 0; jf < 4; ++jf)
                    s[mf][jf] = __builtin_amdgcn_mfma_f32_16x16x32_bf16(
                        qf[mf][kc], kf[jf], s[mf][jf], 0, 0, 0);
        }
        const bool lastt = (kt == nkt - 1);
#pragma unroll
        for (int mf = 0; mf < 2; ++mf) {
#pragma unroll
            for (int r = 0; r < 4; ++r) {
                int rowg = qt * 32 + mf * 16 + lg * 4 + r;
                float tmax = -INFINITY;
#pragma unroll
                for (int jf = 0; jf < 4; ++jf) {
                    float v = s[mf][jf][r] * 0.125f;
                    if (lastt) {
                        int colg = kt * 64 + jf * 16 + lr;
                        if (colg > rowg) v = -INFINITY;
                    }
                    s[mf][jf][r] = v;
                    tmax = fmaxf(tmax, v);
                }
                tmax = fmaxf(tmax, __shfl_xor(tmax, 1, 64));
                tmax = fmaxf(tmax, __shfl_xor(tmax, 2, 64));
                tmax = fmaxf(tmax, __shfl_xor(tmax, 4, 64));
                tmax = fmaxf(tmax, __shfl_xor(tmax, 8, 64));
                float mnew = fmaxf(mrow[mf][r], tmax);
                float corr = __expf(mrow[mf][r] - mnew);
                float ps = 0.0f;
#pragma unroll
                for (int jf = 0; jf < 4; ++jf) {
                    float p = __expf(s[mf][jf][r] - mnew);
                    s[mf][jf][r] = p;
                    ps += p;
                }
                ps += __shfl_xor(ps, 1, 64);
                ps += __shfl_xor(ps, 2, 64);
                ps += __shfl_xor(ps, 4, 64);
                ps += __shfl_xor(ps, 8, 64);
                lsum[mf][r] = lsum[mf][r] * corr + ps;
                mrow[mf][r] = mnew;
#pragma unroll
                for (int nf = 0; nf < 4; ++nf) oacc[mf][nf][r] *= corr;
            }
        }
#pragma unroll
        for (int mf = 0; mf < 2; ++mf)
#pragma unroll
            for (int jf = 0; jf < 4; ++jf)
#pragma unroll
                for (int r = 0; r < 4; ++r)
                    Ps[mf * 16 + lg * 4 + r][jf * 16 + lr] = f2bf(s[mf][jf][r]);
        __syncthreads();
#pragma unroll
        for (int kc = 0; kc < 2; ++kc) {
            bf16x8 pf[2], vf[4];
#pragma unroll
            for (int mf = 0; mf < 2; ++mf)
                pf[mf] = *reinterpret_cast<const bf16x8*>(&Ps[mf * 16 + lr][kc * 32 + lg * 8]);
#pragma unroll
            for (int nf = 0; nf < 4; ++nf)
                vf[nf] = *reinterpret_cast<const bf16x8*>(&Vs[nf * 16 + lr][kc * 32 + lg * 8]);
#pragma unroll
            for (int mf = 0; mf < 2; ++mf)
#pragma unroll
                for (int nf = 0; nf < 4; ++nf)
                    oacc[mf][nf] = __builtin_amdgcn_mfma_f32_16x16x32_bf16(
                        pf[mf], vf[nf], oacc[mf][nf], 0, 0, 0);
        }
    }

    unsigned short* ob = o + (size_t)(b * NT + qt * 32) * NC + h * 64;
#pragma unroll
    for (int mf = 0; mf < 2; ++mf)
#pragma unroll
        for (int nf = 0; nf < 4; ++nf)
#pragma unroll
            for (int r = 0; r < 4; ++r) {
                float v = oacc[mf][nf][r] / lsum[mf][r];
                ob[(size_t)(mf * 16 + lg * 4 + r) * NC + nf * 16 + lr] = f2bf(v);
            }
}

extern "C" void kernel_launch(void* const* d_in, const int* in_sizes, int n_in,
                              void* d_out, int out_size, void* d_ws, size_t ws_size,
                              hipStream_t stream) {
    (void)in_sizes; (void)n_in; (void)out_size; (void)ws_size;
    const int*   idx    = (const int*)  d_in[0];
    const float* tok    = (const float*)d_in[1];
    const float* pos    = (const float*)d_in[2];
    const float* qkv_w  = (const float*)d_in[3];
    const float* qkv_b  = (const float*)d_in[4];
    const float* out_w  = (const float*)d_in[5];
    const float* out_b  = (const float*)d_in[6];
    const float* ln1_s  = (const float*)d_in[7];
    const float* ln1_b  = (const float*)d_in[8];
    const float* ln2_s  = (const float*)d_in[9];
    const float* ln2_b  = (const float*)d_in[10];
    const float* ffn_w1 = (const float*)d_in[11];
    const float* ffn_b1 = (const float*)d_in[12];
    const float* ffn_w2 = (const float*)d_in[13];
    const float* ffn_b2 = (const float*)d_in[14];
    const float* lnf_s  = (const float*)d_in[15];
    const float* lnf_b  = (const float*)d_in[16];

    char* p = (char*)d_ws;
    float* x              = (float*)p;          p += (size_t)NM * NC * 4;
    unsigned short* hbuf  = (unsigned short*)p; p += (size_t)NM * NC * 2;
    unsigned short* qkvb  = (unsigned short*)p; p += (size_t)NM * 3 * NC * 2;
    unsigned short* obuf  = (unsigned short*)p; p += (size_t)NM * NC * 2;
    unsigned short* gbuf  = (unsigned short*)p; p += (size_t)NM * NFF * 2;
    unsigned short* vtb   = (unsigned short*)p; p += (size_t)NB * NH * 64 * NT * 2;
    unsigned short* wq    = (unsigned short*)p; p += (size_t)3 * NC * NC * 2;
    unsigned short* wo    = (unsigned short*)p; p += (size_t)NC * NC * 2;
    unsigned short* w1    = (unsigned short*)p; p += (size_t)NC * NFF * 2;
    unsigned short* w2    = (unsigned short*)p; p += (size_t)NFF * NC * 2;
    unsigned short* temb  = (unsigned short*)p; p += (size_t)NV * NC * 2;

    {
        size_t n4 = (size_t)NV * NC / 4;
        int blocks = (int)((n4 + 255) / 256);
        cvt_bf16_kernel<<<blocks, 256, 0, stream>>>(tok, temb, n4);
    }
    embed_kernel<<<NM, 256, 0, stream>>>(idx, tok, pos, x);

    for (int l = 0; l < NL; ++l) {
        wtrans4_kernel<<<12288, dim3(32, 8), 0, stream>>>(
            qkv_w + (size_t)l * NC * 3 * NC, out_w + (size_t)l * NC * NC,
            ffn_w1 + (size_t)l * NC * NFF, ffn_w2 + (size_t)l * NFF * NC,
            wq, wo, w1, w2);

        ln_kernel<<<NM, 256, 0, stream>>>(x, ln1_s + (size_t)l * NC, ln1_b + (size_t)l * NC, hbuf);
        gemm_kernel<0, true, true, false><<<dim3(16, 24), 256, 0, stream>>>(
            hbuf, wq, qkv_b + (size_t)l * 3 * NC, qkvb, 3 * NC, NC, 3 * NC, NC);
        vtrans_kernel<<<dim3(32, 2, 32), dim3(32, 8), 0, stream>>>(qkvb, vtb);
        attn_kernel<<<dim3(32, 16, 2), 64, 0, stream>>>(qkvb, vtb, obuf);
        gemm_kernel<0, true, false, true><<<dim3(16, 8, 2), 256, 0, stream>>>(
            obuf, wo, out_b + (size_t)l * NC, x, NC, NC, NC, NC / 2);
        ln_kernel<<<NM, 256, 0, stream>>>(x, ln2_s + (size_t)l * NC, ln2_b + (size_t)l * NC, hbuf);
        gemm_kernel<1, true, true, false><<<dim3(16, 32), 256, 0, stream>>>(
            hbuf, w1, ffn_b1 + (size_t)l * NFF, gbuf, NFF, NC, NFF, NC);
        gemm_kernel<0, true, false, true><<<dim3(16, 8, 4), 256, 0, stream>>>(
            gbuf, w2, ffn_b2 + (size_t)l * NC, x, NC, NFF, NC, NFF / 4);
    }
    ln_kernel<<<NM, 256, 0, stream>>>(x, lnf_s, lnf_b, hbuf);
    head_gemm_kernel<<<dim3(8 * 197), 512, 0, stream>>>(hbuf, temb, (float*)d_out, NV, NC);
}